// Round 3
// baseline (423.853 us; speedup 1.0000x reference)
//
#include <hip/hip_runtime.h>
#include <math.h>

typedef unsigned short u16;
typedef short bf8 __attribute__((ext_vector_type(8)));      // 8 bf16 (raw bits)
typedef float f32x4 __attribute__((ext_vector_type(4)));

__device__ __forceinline__ u16 f2b(float f) {
    union { float f; unsigned u; } x; x.f = f;
    return (u16)((x.u + 0x7FFFu + ((x.u >> 16) & 1u)) >> 16);   // RTNE
}
__device__ __forceinline__ float b2f(u16 b) {
    union { unsigned u; float f; } x; x.u = ((unsigned)b) << 16;
    return x.f;
}

__device__ __forceinline__ void async16(const void* g, void* l) {
    __builtin_amdgcn_global_load_lds(
        (const __attribute__((address_space(1))) unsigned int*)g,
        (__attribute__((address_space(3))) unsigned int*)l, 16, 0, 0);
}

__device__ __forceinline__ void cstore(float* p, float v) { *p = v; }
__device__ __forceinline__ void cstore(u16* p, float v) { *p = f2b(v); }

// ---------------- bf16 MFMA GEMM (m97 structure): C[M,N] = A[M,K] @ Bt[N,K]^T ------
template<typename OutT>
__global__ __launch_bounds__(256) void gemm_mfma(const u16* __restrict__ A,
                                                 const u16* __restrict__ Bt,
                                                 OutT* __restrict__ C,
                                                 int M, int N, int K) {
    __shared__ __align__(16) u16 As[128 * 32];
    __shared__ __align__(16) u16 Bs[128 * 32];
    const int tid = threadIdx.x;
    const int w = tid >> 6, L = tid & 63;
    const int l15 = L & 15, quad = L >> 4;
    const int wm = (w >> 1) * 64, wn = (w & 1) * 64;
    const int row0 = blockIdx.y * 128, col0 = blockIdx.x * 128;
    const int laneRow = L >> 2, laneCol8 = (L & 3) * 8;

    f32x4 acc[4][4] = {};

    for (int k0 = 0; k0 < K; k0 += 32) {
        #pragma unroll
        for (int i = 0; i < 2; ++i) {
            const int seg = w * 2 + i;
            const int r = seg * 16 + laneRow;
            async16(&A[(size_t)(row0 + r) * K + k0 + laneCol8], &As[seg * 512 + L * 8]);
        }
        #pragma unroll
        for (int i = 0; i < 2; ++i) {
            const int seg = w * 2 + i;
            const int r = seg * 16 + laneRow;
            async16(&Bt[(size_t)(col0 + r) * K + k0 + laneCol8], &Bs[seg * 512 + L * 8]);
        }
        __syncthreads();
        bf8 a[4], b[4];
        #pragma unroll
        for (int mt = 0; mt < 4; ++mt)
            a[mt] = *(const bf8*)&As[(wm + mt * 16 + l15) * 32 + quad * 8];
        #pragma unroll
        for (int nt = 0; nt < 4; ++nt)
            b[nt] = *(const bf8*)&Bs[(wn + nt * 16 + l15) * 32 + quad * 8];
        #pragma unroll
        for (int mt = 0; mt < 4; ++mt)
            #pragma unroll
            for (int nt = 0; nt < 4; ++nt)
                acc[mt][nt] = __builtin_amdgcn_mfma_f32_16x16x32_bf16(
                    a[mt], b[nt], acc[mt][nt], 0, 0, 0);
        __syncthreads();
    }
    #pragma unroll
    for (int mt = 0; mt < 4; ++mt)
        #pragma unroll
        for (int nt = 0; nt < 4; ++nt) {
            const int col = col0 + wn + nt * 16 + l15;
            #pragma unroll
            for (int r = 0; r < 4; ++r) {
                const int row = row0 + wm + mt * 16 + quad * 4 + r;
                cstore(&C[(size_t)row * N + col], acc[mt][nt][r]);
            }
        }
}

// ---------------- merged prep: x->bf16, EKP/EVP fragment tables, weight transposes --
__global__ __launch_bounds__(256) void prep_all(const float* __restrict__ x,
                                                const float* __restrict__ embk,
                                                const float* __restrict__ embv,
                                                const float* __restrict__ w_attn,
                                                const float* __restrict__ w_proj,
                                                u16* __restrict__ xb,
                                                u16* __restrict__ EKP,
                                                u16* __restrict__ EVP,
                                                u16* __restrict__ waT,
                                                u16* __restrict__ wpT) {
    __shared__ u16 ts[64][65];
    const int bx = blockIdx.x;
    const int tid = threadIdx.x;
    if (bx < 4096) {
        int idx = bx * 256 + tid;
        const float4 v = ((const float4*)x)[idx];
        ((ushort4*)xb)[idx] = make_ushort4(f2b(v.x), f2b(v.y), f2b(v.z), f2b(v.w));
    } else if (bx < 4132) {
        int t = (bx - 4096) * 256 + tid;           // [0, 9216)
        int L = t & 63, kc = (t >> 6) & 1, k16 = t >> 7;
        int l15 = L & 15, quad = L >> 4;
        int row = 1 + k16 * 16 + l15;
        int d = row - 128;
        int cl = d < 0 ? 0 : (d > 1023 ? 1023 : d);
        const float* p = embk + cl * 64 + kc * 32 + quad * 8;
        #pragma unroll
        for (int i = 0; i < 8; ++i) EKP[t * 8 + i] = f2b(p[i]);
    } else if (bx < 4168) {
        int t = (bx - 4132) * 256 + tid;           // [0, 9216)
        int L = t & 63, rest = t >> 6;             // rest = tn*36 + c32
        int c32 = rest % 36, tn = rest / 36;
        int l15 = L & 15, quad = L >> 4;
        #pragma unroll
        for (int i = 0; i < 8; ++i) {
            int c = c32 * 32 + quad * 8 + i;
            int d = c - 127;
            int cl = d < 0 ? 0 : (d > 1023 ? 1023 : d);
            EVP[t * 8 + i] = f2b(embv[cl * 64 + tn * 16 + l15]);
        }
    } else {
        const float* W; u16* WT; int Cc, t;
        if (bx < 4168 + 768) { t = bx - 4168; W = w_attn; WT = waT; Cc = 3072; }
        else                 { t = bx - 4936; W = w_proj; WT = wpT; Cc = 1024; }
        const int nx = Cc >> 6;
        const int c0 = (t % nx) * 64, r0 = (t / nx) * 64;
        for (int i = tid; i < 4096; i += 256) {
            int r = i >> 6, c = i & 63;
            ts[r][c] = f2b(W[(size_t)(r0 + r) * Cc + c0 + c]);
        }
        __syncthreads();
        for (int i = tid; i < 4096; i += 256) {
            int c = i >> 6, r = i & 63;
            WT[(size_t)(c0 + c) * 1024 + r0 + r] = ts[r][c];
        }
    }
}

// ---------------- prep: V^T bf16   Vt[64bh*64 + d][1024 s]  (from bf16 qkv) --------
__global__ __launch_bounds__(256) void prep_vt(const u16* __restrict__ qkvb,
                                               u16* __restrict__ Vt) {
    __shared__ u16 ts[64][65];
    const int tid = threadIdx.x;
    const int s0 = blockIdx.x * 64;
    const int bh = blockIdx.y, b = bh >> 4, h = bh & 15;
    #pragma unroll
    for (int it = 0; it < 4; ++it) {
        int s = it * 16 + (tid >> 4);
        int d4 = (tid & 15) * 4;
        const u16* p = qkvb + (size_t)(b * 1024 + s0 + s) * 3072 + 2048 + h * 64 + d4;
        #pragma unroll
        for (int i = 0; i < 4; ++i) ts[s][d4 + i] = p[i];
    }
    __syncthreads();
    const int d = tid >> 2, si = (tid & 3) * 16;
    __align__(16) u16 buf[16];
    #pragma unroll
    for (int i = 0; i < 16; ++i) buf[i] = ts[si + i][d];
    u16* o = Vt + ((size_t)(bh * 64 + d) << 10) + s0 + si;
    *(uint4*)o       = ((uint4*)buf)[0];
    *(uint4*)(o + 8) = ((uint4*)buf)[1];
}

// ---------------- pack K (pre-scaled by 1/8) and V into B-fragment-linear tables ----
__global__ __launch_bounds__(256) void pack_kv(const u16* __restrict__ qkvb,
                                               const u16* __restrict__ Vt,
                                               u16* __restrict__ Kp,
                                               u16* __restrict__ Vp) {
    const int bx = blockIdx.x;
    if (bx < 2048) {
        int t = bx * 256 + threadIdx.x;            // [0, 524288)
        int L = t & 63, kc = (t >> 6) & 1, s16 = (t >> 7) & 63, bh = t >> 13;
        int l15 = L & 15, quad = L >> 4;
        int b = bh >> 4, h = bh & 15;
        const u16* src = qkvb + (size_t)(b * 1024 + s16 * 16 + l15) * 3072
                       + 1024 + h * 64 + kc * 32 + quad * 8;
        u16* dst = Kp + (size_t)t * 8;
        #pragma unroll
        for (int i = 0; i < 8; ++i) dst[i] = f2b(b2f(src[i]) * 0.125f);
    } else {
        int t = (bx - 2048) * 256 + threadIdx.x;   // [0, 524288)
        int L = t & 63, c32 = (t >> 6) & 31, tn = (t >> 11) & 3, bh = t >> 13;
        int l15 = L & 15, quad = L >> 4;
        const u16* src = Vt + ((size_t)(bh * 64 + tn * 16 + l15) << 10)
                       + c32 * 32 + quad * 8;
        *(uint4*)(Vp + (size_t)t * 8) = *(const uint4*)src;
    }
}

// cumulative chunk counts: tile t owns units [S(t), S(t)+t/2+1); S(16)=72 total.
__device__ const int d_S[17] = {0,1,2,4,6,9,12,16,20,25,30,36,42,49,56,64,72};
// partial-slot base per split tile (tiles 4, 8..15), compact: 19 slots per bh.
// tile:       0  1  2  3  4  5  6  7  8  9 10 11 12 13 14 15
__device__ const int d_SB[16] = {0,0,0,0, 0,0,0,0, 2, 4, 6, 8,10,13,15,17};

// ---------------- MFMA fused attention with RPE: unit-split for 2x wave parallelism -
// Work = 72 equal-cost units per bh (unit = 64 Q-rows x 128 cols chunk).
// grid (18, 64): block k owns units [4k, 4k+4) of the canonical
// (tile-ascending, chunk-ascending) order -> 1152 perfectly balanced blocks,
// 4 blocks/CU resident (LDS 36.9KB, __launch_bounds__(256,4)) = 16 waves/CU.
// A tile is finalized inline iff all its units live in ONE block, decided
// structurally: (S(t)>>2) == ((S(t+1)-1)>>2). (R2 bug: tile 4 spans blocks
// 1 and 2 — the old `t<8` test raced two finalizes on yb.) Split tiles
// {4, 8..15} flush f32 partials (o, lsum) to statically-indexed slots
// (additive: softmax uses fixed exp bias, no running max); attn_reduce sums
// <=3 slots and normalizes. K/V fragments read directly from fragment-linear
// global tables (L2-resident); no barriers anywhere, all LDS per-wave.
__global__ __launch_bounds__(256, 4) void attn_mfma(const u16* __restrict__ qkvb,
                                                    const u16* __restrict__ Kp,
                                                    const u16* __restrict__ Vp,
                                                    const u16* __restrict__ EKP,
                                                    const u16* __restrict__ EVP,
                                                    u16* __restrict__ yb,
                                                    float* __restrict__ po,
                                                    float* __restrict__ lsp) {
    __shared__ __align__(16) u16 slab_[4][4608];   // 36864 B, per-wave overlay

    const int tid = threadIdx.x;
    const int w = tid >> 6, L = tid & 63;
    const int l15 = L & 15, quad = L >> 4;
    const int blk = blockIdx.x;
    const int bh = blockIdx.y, b = bh >> 4, h = bh & 15;
    u16* S2l = slab_[w];
    u16* Pl  = slab_[w];
    u16* Ppl = slab_[w] + 2048;

    const bf8* EKPF = (const bf8*)EKP;
    const bf8* EVPF = (const bf8*)EVP;
    const bf8* KPF  = (const bf8*)Kp;
    const bf8* VPF  = (const bf8*)Vp;

    bf8 qn[2];
    f32x4 o[4];
    float lsum[4];
    int t = -1, t0 = 0;

    auto flush = [&](int tt) {
        float lr[4];
        #pragma unroll
        for (int r = 0; r < 4; ++r) {
            float s = lsum[r];
            s += __shfl_xor(s, 1); s += __shfl_xor(s, 2);
            s += __shfl_xor(s, 4); s += __shfl_xor(s, 8);
            lr[r] = s;
        }
        const bool whole = (d_S[tt] >> 2) == ((d_S[tt + 1] - 1) >> 2);
        if (whole) {           // all units of this tile in this block: finalize
            #pragma unroll
            for (int tn = 0; tn < 4; ++tn) {
                const int col = h * 64 + tn * 16 + l15;
                #pragma unroll
                for (int r = 0; r < 4; ++r) {
                    const int trow = tt * 64 + w * 16 + quad * 4 + r;
                    yb[(size_t)(b * 1024 + trow) * 1024 + col] = f2b(o[tn][r] / lr[r]);
                }
            }
        } else {               // partial: statically-indexed slot
            const int slot = blk - (d_S[tt] >> 2);
            const size_t sidx = (size_t)(bh * 19 + d_SB[tt] + slot);
            float* pob = po + (sidx << 12);
            #pragma unroll
            for (int tn = 0; tn < 4; ++tn)
                #pragma unroll
                for (int r = 0; r < 4; ++r)
                    pob[(w * 16 + quad * 4 + r) * 64 + tn * 16 + l15] = o[tn][r];
            if (l15 == 0) {
                float* lsb = lsp + (sidx << 6);
                #pragma unroll
                for (int r = 0; r < 4; ++r) lsb[w * 16 + quad * 4 + r] = lr[r];
            }
        }
    };

    #pragma unroll 1
    for (int ui = 0; ui < 4; ++ui) {
        const int u = blk * 4 + ui;
        int nt = (t < 0) ? 0 : t;
        while (d_S[nt + 1] <= u) ++nt;
        if (nt != t) {
            if (t >= 0) flush(t);
            t = nt; t0 = t * 64;
            const int trow = t0 + w * 16 + l15;
            const u16* qp = qkvb + (size_t)(b * 1024 + trow) * 3072 + h * 64 + quad * 8;
            qn[0] = *(const bf8*)qp;
            qn[1] = *(const bf8*)(qp + 32);
            #pragma unroll
            for (int tn = 0; tn < 4; ++tn)
                #pragma unroll
                for (int j = 0; j < 4; ++j) o[tn][j] = 0.f;
            #pragma unroll
            for (int r = 0; r < 4; ++r) lsum[r] = 0.f;
        }
        const int c = u - d_S[t];
        const int s0 = c << 7;
        const int diff = t0 - s0;                 // >= 0, multiple of 64

        // ---- S2 = Q @ EK^T (global EKP stream) ----
        f32x4 s2[9] = {};
        {
            const int kb = (diff >> 4) + w;       // k16 base
            #pragma unroll
            for (int j = 0; j < 9; ++j) {
                #pragma unroll
                for (int kc = 0; kc < 2; ++kc)
                    s2[j] = __builtin_amdgcn_mfma_f32_16x16x32_bf16(
                        qn[kc], EKPF[(((kb + j) << 1) + kc) * 64 + L], s2[j], 0, 0, 0);
            }
        }
        #pragma unroll
        for (int j = 0; j < 9; ++j)
            #pragma unroll
            for (int r = 0; r < 4; ++r)
                S2l[(quad * 4 + r) * 148 + j * 16 + l15] = f2b(s2[j][r]);

        // ---- S1 = Q @ (K/8)^T (global Kp fragment stream) ----
        f32x4 s1[8] = {};
        {
            const int kb0 = bh * 64 + (s0 >> 4);
            #pragma unroll
            for (int tn = 0; tn < 8; ++tn) {
                #pragma unroll
                for (int kc = 0; kc < 2; ++kc) {
                    const bf8 kf = KPF[(size_t)((kb0 + tn) * 2 + kc) * 64 + L];
                    s1[tn] = __builtin_amdgcn_mfma_f32_16x16x32_bf16(
                        qn[kc], kf, s1[tn], 0, 0, 0);
                }
            }
        }

        // ---- logits + mask + p = exp(logit - 4); per-lane partial sums ----
        #pragma unroll
        for (int tn = 0; tn < 8; ++tn) {
            const int cl = tn * 16 + l15;
            #pragma unroll
            for (int r = 0; r < 4; ++r) {
                const int row = quad * 4 + r;
                float v = s1[tn][r] + b2f(S2l[row * 148 + (row - cl + 127)]);
                if (cl > diff + w * 16 + row) v = -1e30f;
                float p = __expf(v - 4.0f);       // masked -> 0
                s1[tn][r] = p;
                lsum[r] += p;
            }
        }
        // ---- zero P' slab (AFTER shear reads; pad entries must be 0) ----
        #pragma unroll
        for (int i = 0; i < 5; ++i)
            ((uint4*)Ppl)[i * 64 + L] = make_uint4(0, 0, 0, 0);
        // ---- scatter P and sheared P' in MFMA A-layout ----
        #pragma unroll
        for (int tn = 0; tn < 8; ++tn) {
            const int cl = tn * 16 + l15;
            #pragma unroll
            for (int r = 0; r < 4; ++r) {
                const int row = quad * 4 + r;
                const u16 pb = f2b(s1[tn][r]);
                Pl[((cl >> 5) << 9) + (((cl >> 3) & 3) << 7) + (row << 3) + (cl & 7)] = pb;
                const int dc = (w & 1) * 16 + row - cl + 127;   // [0,158]
                Ppl[((dc >> 5) << 9) + (((dc >> 3) & 3) << 7) + (row << 3) + (dc & 7)] = pb;
            }
        }

        // ---- O += P @ V (global Vp fragment stream) ----
        {
            bf8 pa[4];
            #pragma unroll
            for (int kc = 0; kc < 4; ++kc) pa[kc] = ((const bf8*)Pl)[kc * 64 + L];
            const int vb0 = bh * 128 + (s0 >> 5);
            #pragma unroll
            for (int tn = 0; tn < 4; ++tn) {
                #pragma unroll
                for (int kc = 0; kc < 4; ++kc) {
                    const bf8 vf = VPF[(size_t)(vb0 + tn * 32 + kc) * 64 + L];
                    o[tn] = __builtin_amdgcn_mfma_f32_16x16x32_bf16(
                        pa[kc], vf, o[tn], 0, 0, 0);
                }
            }
        }
        // ---- O += P' @ EV (global EVP stream) ----
        {
            bf8 pa[5];
            #pragma unroll
            for (int kc = 0; kc < 5; ++kc) pa[kc] = ((const bf8*)Ppl)[kc * 64 + L];
            const int eb = (diff >> 5) + (w >> 1);
            #pragma unroll
            for (int tn = 0; tn < 4; ++tn) {
                #pragma unroll
                for (int kc = 0; kc < 5; ++kc)
                    o[tn] = __builtin_amdgcn_mfma_f32_16x16x32_bf16(
                        pa[kc], EVPF[(tn * 36 + eb + kc) * 64 + L], o[tn], 0, 0, 0);
            }
        }
    }
    flush(t);
}

// ---------------- combine partial (o, lsum) slots for split tiles, normalize -------
__global__ __launch_bounds__(256) void attn_reduce(const float* __restrict__ po,
                                                   const float* __restrict__ lsp,
                                                   u16* __restrict__ yb) {
    const int gi = blockIdx.x;                    // 0 -> tile 4, i -> tile i+7
    const int t = (gi == 0) ? 4 : (gi + 7);
    const int bh = blockIdx.y, b = bh >> 4, h = bh & 15;
    const int ns = (t == 12) ? 3 : 2;
    const size_t base = (size_t)(bh * 19 + d_SB[t]);
    const float* pob = po + (base << 12);
    const float* lsb = lsp + (base << 6);
    #pragma unroll 1
    for (int i = 0; i < 16; ++i) {
        const int idx = i * 256 + threadIdx.x;
        const int row = idx >> 6, col = idx & 63;
        float acc = 0.f, lacc = 0.f;
        for (int s = 0; s < ns; ++s) {
            acc  += pob[(s << 12) + idx];
            lacc += lsb[(s << 6) + row];
        }
        yb[(size_t)(b * 1024 + t * 64 + row) * 1024 + h * 64 + col] = f2b(acc / lacc);
    }
}

extern "C" void kernel_launch(void* const* d_in, const int* in_sizes, int n_in,
                              void* d_out, int out_size, void* d_ws, size_t ws_size,
                              hipStream_t stream) {
    const float* x      = (const float*)d_in[0];
    const float* w_attn = (const float*)d_in[1];
    const float* w_proj = (const float*)d_in[2];
    const float* embk   = (const float*)d_in[3];
    const float* embv   = (const float*)d_in[4];
    float* out = (float*)d_out;

    u16* wsb   = (u16*)d_ws;
    u16* qkvb  = wsb;                  // 4096*3072            = 12582912
    u16* xb    = qkvb + 12582912;      // 4096*1024            = 4194304
    u16* ymidb = xb;                   // aliases xb (xb dead after gemm1)
    u16* waT   = xb + 4194304;         // 3072*1024            = 3145728
    u16* wpT   = waT + 3145728;        // 1024*1024            = 1048576
    u16* Vt    = wpT + 1048576;        // 64*64*1024           = 4194304
    u16* Kp    = Vt + 4194304;         // 64*64*2*512          = 4194304
    u16* Vp    = Kp + 4194304;         // 64*4*32*512          = 4194304
    u16* EKP   = Vp + 4194304;         // 72*2*512             = 73728
    u16* EVP   = EKP + 73728;          // 4*36*512             = 73728
    float* po  = (float*)(EVP + 73728);// 64*19*4096 f32       = 4980736 f32
    float* lsp = po + 4980736;         // 64*19*64 f32         = 77824 f32

    prep_all<<<dim3(5192), 256, 0, stream>>>(x, embk, embv, w_attn, w_proj,
                                             xb, EKP, EVP, waT, wpT);
    gemm_mfma<u16><<<dim3(24, 32), 256, 0, stream>>>(xb, waT, qkvb, 4096, 3072, 1024);
    prep_vt<<<dim3(16, 64), 256, 0, stream>>>(qkvb, Vt);
    pack_kv<<<dim3(4096), 256, 0, stream>>>(qkvb, Vt, Kp, Vp);
    attn_mfma<<<dim3(18, 64), 256, 0, stream>>>(qkvb, Kp, Vp, EKP, EVP, ymidb, po, lsp);
    attn_reduce<<<dim3(9, 64), 256, 0, stream>>>(po, lsp, ymidb);
    gemm_mfma<float><<<dim3(8, 32), 256, 0, stream>>>(ymidb, wpT, out, 4096, 1024, 1024);
}

// Round 4
// 364.954 us; speedup vs baseline: 1.1614x; 1.1614x over previous
//
#include <hip/hip_runtime.h>
#include <math.h>

typedef unsigned short u16;
typedef short bf8 __attribute__((ext_vector_type(8)));      // 8 bf16 (raw bits)
typedef float f32x4 __attribute__((ext_vector_type(4)));

__device__ __forceinline__ u16 f2b(float f) {
    union { float f; unsigned u; } x; x.f = f;
    return (u16)((x.u + 0x7FFFu + ((x.u >> 16) & 1u)) >> 16);   // RTNE
}
__device__ __forceinline__ float b2f(u16 b) {
    union { unsigned u; float f; } x; x.u = ((unsigned)b) << 16;
    return x.f;
}

__device__ __forceinline__ void async16(const void* g, void* l) {
    __builtin_amdgcn_global_load_lds(
        (const __attribute__((address_space(1))) unsigned int*)g,
        (__attribute__((address_space(3))) unsigned int*)l, 16, 0, 0);
}

__device__ __forceinline__ void cstore(float* p, float v) { *p = v; }
__device__ __forceinline__ void cstore(u16* p, float v) { *p = f2b(v); }

// ---------------- bf16 MFMA GEMM (m97 structure): C[M,N] = A[M,K] @ Bt[N,K]^T ------
template<typename OutT>
__global__ __launch_bounds__(256) void gemm_mfma(const u16* __restrict__ A,
                                                 const u16* __restrict__ Bt,
                                                 OutT* __restrict__ C,
                                                 int M, int N, int K) {
    __shared__ __align__(16) u16 As[128 * 32];
    __shared__ __align__(16) u16 Bs[128 * 32];
    const int tid = threadIdx.x;
    const int w = tid >> 6, L = tid & 63;
    const int l15 = L & 15, quad = L >> 4;
    const int wm = (w >> 1) * 64, wn = (w & 1) * 64;
    const int row0 = blockIdx.y * 128, col0 = blockIdx.x * 128;
    const int laneRow = L >> 2, laneCol8 = (L & 3) * 8;

    f32x4 acc[4][4] = {};

    for (int k0 = 0; k0 < K; k0 += 32) {
        #pragma unroll
        for (int i = 0; i < 2; ++i) {
            const int seg = w * 2 + i;
            const int r = seg * 16 + laneRow;
            async16(&A[(size_t)(row0 + r) * K + k0 + laneCol8], &As[seg * 512 + L * 8]);
        }
        #pragma unroll
        for (int i = 0; i < 2; ++i) {
            const int seg = w * 2 + i;
            const int r = seg * 16 + laneRow;
            async16(&Bt[(size_t)(col0 + r) * K + k0 + laneCol8], &Bs[seg * 512 + L * 8]);
        }
        __syncthreads();
        bf8 a[4], b[4];
        #pragma unroll
        for (int mt = 0; mt < 4; ++mt)
            a[mt] = *(const bf8*)&As[(wm + mt * 16 + l15) * 32 + quad * 8];
        #pragma unroll
        for (int nt = 0; nt < 4; ++nt)
            b[nt] = *(const bf8*)&Bs[(wn + nt * 16 + l15) * 32 + quad * 8];
        #pragma unroll
        for (int mt = 0; mt < 4; ++mt)
            #pragma unroll
            for (int nt = 0; nt < 4; ++nt)
                acc[mt][nt] = __builtin_amdgcn_mfma_f32_16x16x32_bf16(
                    a[mt], b[nt], acc[mt][nt], 0, 0, 0);
        __syncthreads();
    }
    #pragma unroll
    for (int mt = 0; mt < 4; ++mt)
        #pragma unroll
        for (int nt = 0; nt < 4; ++nt) {
            const int col = col0 + wn + nt * 16 + l15;
            #pragma unroll
            for (int r = 0; r < 4; ++r) {
                const int row = row0 + wm + mt * 16 + quad * 4 + r;
                cstore(&C[(size_t)row * N + col], acc[mt][nt][r]);
            }
        }
}

// ---------------- merged prep: x->bf16, EKP/EVP fragment tables, weight transposes --
__global__ __launch_bounds__(256) void prep_all(const float* __restrict__ x,
                                                const float* __restrict__ embk,
                                                const float* __restrict__ embv,
                                                const float* __restrict__ w_attn,
                                                const float* __restrict__ w_proj,
                                                u16* __restrict__ xb,
                                                u16* __restrict__ EKP,
                                                u16* __restrict__ EVP,
                                                u16* __restrict__ waT,
                                                u16* __restrict__ wpT) {
    __shared__ u16 ts[64][65];
    const int bx = blockIdx.x;
    const int tid = threadIdx.x;
    if (bx < 4096) {
        int idx = bx * 256 + tid;
        const float4 v = ((const float4*)x)[idx];
        ((ushort4*)xb)[idx] = make_ushort4(f2b(v.x), f2b(v.y), f2b(v.z), f2b(v.w));
    } else if (bx < 4132) {
        int t = (bx - 4096) * 256 + tid;           // [0, 9216)
        int L = t & 63, kc = (t >> 6) & 1, k16 = t >> 7;
        int l15 = L & 15, quad = L >> 4;
        int row = 1 + k16 * 16 + l15;
        int d = row - 128;
        int cl = d < 0 ? 0 : (d > 1023 ? 1023 : d);
        const float* p = embk + cl * 64 + kc * 32 + quad * 8;
        #pragma unroll
        for (int i = 0; i < 8; ++i) EKP[t * 8 + i] = f2b(p[i]);
    } else if (bx < 4168) {
        int t = (bx - 4132) * 256 + tid;           // [0, 9216)
        int L = t & 63, rest = t >> 6;             // rest = tn*36 + c32
        int c32 = rest % 36, tn = rest / 36;
        int l15 = L & 15, quad = L >> 4;
        #pragma unroll
        for (int i = 0; i < 8; ++i) {
            int c = c32 * 32 + quad * 8 + i;
            int d = c - 127;
            int cl = d < 0 ? 0 : (d > 1023 ? 1023 : d);
            EVP[t * 8 + i] = f2b(embv[cl * 64 + tn * 16 + l15]);
        }
    } else {
        const float* W; u16* WT; int Cc, t;
        if (bx < 4168 + 768) { t = bx - 4168; W = w_attn; WT = waT; Cc = 3072; }
        else                 { t = bx - 4936; W = w_proj; WT = wpT; Cc = 1024; }
        const int nx = Cc >> 6;
        const int c0 = (t % nx) * 64, r0 = (t / nx) * 64;
        for (int i = tid; i < 4096; i += 256) {
            int r = i >> 6, c = i & 63;
            ts[r][c] = f2b(W[(size_t)(r0 + r) * Cc + c0 + c]);
        }
        __syncthreads();
        for (int i = tid; i < 4096; i += 256) {
            int c = i >> 6, r = i & 63;
            WT[(size_t)(c0 + c) * 1024 + r0 + r] = ts[r][c];
        }
    }
}

// ---------------- prep: V^T bf16   Vt[64bh*64 + d][1024 s]  (from bf16 qkv) --------
__global__ __launch_bounds__(256) void prep_vt(const u16* __restrict__ qkvb,
                                               u16* __restrict__ Vt) {
    __shared__ u16 ts[64][65];
    const int tid = threadIdx.x;
    const int s0 = blockIdx.x * 64;
    const int bh = blockIdx.y, b = bh >> 4, h = bh & 15;
    #pragma unroll
    for (int it = 0; it < 4; ++it) {
        int s = it * 16 + (tid >> 4);
        int d4 = (tid & 15) * 4;
        const u16* p = qkvb + (size_t)(b * 1024 + s0 + s) * 3072 + 2048 + h * 64 + d4;
        #pragma unroll
        for (int i = 0; i < 4; ++i) ts[s][d4 + i] = p[i];
    }
    __syncthreads();
    const int d = tid >> 2, si = (tid & 3) * 16;
    __align__(16) u16 buf[16];
    #pragma unroll
    for (int i = 0; i < 16; ++i) buf[i] = ts[si + i][d];
    u16* o = Vt + ((size_t)(bh * 64 + d) << 10) + s0 + si;
    *(uint4*)o       = ((uint4*)buf)[0];
    *(uint4*)(o + 8) = ((uint4*)buf)[1];
}

// ---------------- pack K (pre-scaled by 1/8) and V into B-fragment-linear tables ----
__global__ __launch_bounds__(256) void pack_kv(const u16* __restrict__ qkvb,
                                               const u16* __restrict__ Vt,
                                               u16* __restrict__ Kp,
                                               u16* __restrict__ Vp) {
    const int bx = blockIdx.x;
    if (bx < 2048) {
        int t = bx * 256 + threadIdx.x;            // [0, 524288)
        int L = t & 63, kc = (t >> 6) & 1, s16 = (t >> 7) & 63, bh = t >> 13;
        int l15 = L & 15, quad = L >> 4;
        int b = bh >> 4, h = bh & 15;
        const u16* src = qkvb + (size_t)(b * 1024 + s16 * 16 + l15) * 3072
                       + 1024 + h * 64 + kc * 32 + quad * 8;
        u16* dst = Kp + (size_t)t * 8;
        #pragma unroll
        for (int i = 0; i < 8; ++i) dst[i] = f2b(b2f(src[i]) * 0.125f);
    } else {
        int t = (bx - 2048) * 256 + threadIdx.x;   // [0, 524288)
        int L = t & 63, c32 = (t >> 6) & 31, tn = (t >> 11) & 3, bh = t >> 13;
        int l15 = L & 15, quad = L >> 4;
        const u16* src = Vt + ((size_t)(bh * 64 + tn * 16 + l15) << 10)
                       + c32 * 32 + quad * 8;
        *(uint4*)(Vp + (size_t)t * 8) = *(const uint4*)src;
    }
}

// cumulative chunk counts: tile t owns units [S(t), S(t)+t/2+1); S(16)=72 total.
__device__ const int d_S[17] = {0,1,2,4,6,9,12,16,20,25,30,36,42,49,56,64,72};
// partial-slot base per split tile (tiles 4, 8..15), compact: 19 slots per bh.
// tile:       0  1  2  3  4  5  6  7  8  9 10 11 12 13 14 15
__device__ const int d_SB[16] = {0,0,0,0, 0,0,0,0, 2, 4, 6, 8,10,13,15,17};

// ---------------- MFMA fused attention with RPE: unit-split for 2x wave parallelism -
// Work = 72 equal-cost units per bh (unit = 64 Q-rows x 128 cols chunk).
// grid (18, 64): block k owns units [4k, 4k+4) -> 1152 balanced blocks, up to
// 4 blocks/CU (LDS 36.9KB; VGPR ~120 naturally <= 128 so 4 waves/SIMD fit).
// __launch_bounds__(256, 3): cap VGPR at ~170 ONLY to forbid spilling — R3's
// (256,4) squeezed to 64 VGPR and spilled ~220MB of scratch to HBM
// (WRITE_SIZE 8->122MB), tripling kernel time. Do NOT tighten this.
// A tile is finalized inline iff all its units live in ONE block, decided
// structurally: (S(t)>>2) == ((S(t+1)-1)>>2). Split tiles {4, 8..15} flush
// f32 partials (o, lsum) to statically-indexed slots (additive: softmax uses
// fixed exp bias, no running max); attn_reduce sums <=3 slots + normalizes.
// K/V fragments read directly from fragment-linear global tables
// (L2-resident); no barriers anywhere, all LDS per-wave.
__global__ __launch_bounds__(256, 3) void attn_mfma(const u16* __restrict__ qkvb,
                                                    const u16* __restrict__ Kp,
                                                    const u16* __restrict__ Vp,
                                                    const u16* __restrict__ EKP,
                                                    const u16* __restrict__ EVP,
                                                    u16* __restrict__ yb,
                                                    float* __restrict__ po,
                                                    float* __restrict__ lsp) {
    __shared__ __align__(16) u16 slab_[4][4608];   // 36864 B, per-wave overlay

    const int tid = threadIdx.x;
    const int w = tid >> 6, L = tid & 63;
    const int l15 = L & 15, quad = L >> 4;
    const int blk = blockIdx.x;
    const int bh = blockIdx.y, b = bh >> 4, h = bh & 15;
    u16* S2l = slab_[w];
    u16* Pl  = slab_[w];
    u16* Ppl = slab_[w] + 2048;

    const bf8* EKPF = (const bf8*)EKP;
    const bf8* EVPF = (const bf8*)EVP;
    const bf8* KPF  = (const bf8*)Kp;
    const bf8* VPF  = (const bf8*)Vp;

    bf8 qn[2];
    f32x4 o[4];
    float lsum[4];
    int t = -1, t0 = 0;

    auto flush = [&](int tt) {
        float lr[4];
        #pragma unroll
        for (int r = 0; r < 4; ++r) {
            float s = lsum[r];
            s += __shfl_xor(s, 1); s += __shfl_xor(s, 2);
            s += __shfl_xor(s, 4); s += __shfl_xor(s, 8);
            lr[r] = s;
        }
        const bool whole = (d_S[tt] >> 2) == ((d_S[tt + 1] - 1) >> 2);
        if (whole) {           // all units of this tile in this block: finalize
            #pragma unroll
            for (int tn = 0; tn < 4; ++tn) {
                const int col = h * 64 + tn * 16 + l15;
                #pragma unroll
                for (int r = 0; r < 4; ++r) {
                    const int trow = tt * 64 + w * 16 + quad * 4 + r;
                    yb[(size_t)(b * 1024 + trow) * 1024 + col] = f2b(o[tn][r] / lr[r]);
                }
            }
        } else {               // partial: statically-indexed slot
            const int slot = blk - (d_S[tt] >> 2);
            const size_t sidx = (size_t)(bh * 19 + d_SB[tt] + slot);
            float* pob = po + (sidx << 12);
            #pragma unroll
            for (int tn = 0; tn < 4; ++tn)
                #pragma unroll
                for (int r = 0; r < 4; ++r)
                    pob[(w * 16 + quad * 4 + r) * 64 + tn * 16 + l15] = o[tn][r];
            if (l15 == 0) {
                float* lsb = lsp + (sidx << 6);
                #pragma unroll
                for (int r = 0; r < 4; ++r) lsb[w * 16 + quad * 4 + r] = lr[r];
            }
        }
    };

    #pragma unroll 1
    for (int ui = 0; ui < 4; ++ui) {
        const int u = blk * 4 + ui;
        int nt = (t < 0) ? 0 : t;
        while (d_S[nt + 1] <= u) ++nt;
        if (nt != t) {
            if (t >= 0) flush(t);
            t = nt; t0 = t * 64;
            const int trow = t0 + w * 16 + l15;
            const u16* qp = qkvb + (size_t)(b * 1024 + trow) * 3072 + h * 64 + quad * 8;
            qn[0] = *(const bf8*)qp;
            qn[1] = *(const bf8*)(qp + 32);
            #pragma unroll
            for (int tn = 0; tn < 4; ++tn)
                #pragma unroll
                for (int j = 0; j < 4; ++j) o[tn][j] = 0.f;
            #pragma unroll
            for (int r = 0; r < 4; ++r) lsum[r] = 0.f;
        }
        const int c = u - d_S[t];
        const int s0 = c << 7;
        const int diff = t0 - s0;                 // >= 0, multiple of 64

        // ---- S2 = Q @ EK^T (global EKP stream) ----
        f32x4 s2[9] = {};
        {
            const int kb = (diff >> 4) + w;       // k16 base
            #pragma unroll
            for (int j = 0; j < 9; ++j) {
                #pragma unroll
                for (int kc = 0; kc < 2; ++kc)
                    s2[j] = __builtin_amdgcn_mfma_f32_16x16x32_bf16(
                        qn[kc], EKPF[(((kb + j) << 1) + kc) * 64 + L], s2[j], 0, 0, 0);
            }
        }
        #pragma unroll
        for (int j = 0; j < 9; ++j)
            #pragma unroll
            for (int r = 0; r < 4; ++r)
                S2l[(quad * 4 + r) * 148 + j * 16 + l15] = f2b(s2[j][r]);

        // ---- S1 = Q @ (K/8)^T (global Kp fragment stream) ----
        f32x4 s1[8] = {};
        {
            const int kb0 = bh * 64 + (s0 >> 4);
            #pragma unroll
            for (int tn = 0; tn < 8; ++tn) {
                #pragma unroll
                for (int kc = 0; kc < 2; ++kc) {
                    const bf8 kf = KPF[(size_t)((kb0 + tn) * 2 + kc) * 64 + L];
                    s1[tn] = __builtin_amdgcn_mfma_f32_16x16x32_bf16(
                        qn[kc], kf, s1[tn], 0, 0, 0);
                }
            }
        }

        // ---- logits + mask + p = exp(logit - 4); per-lane partial sums ----
        #pragma unroll
        for (int tn = 0; tn < 8; ++tn) {
            const int cl = tn * 16 + l15;
            #pragma unroll
            for (int r = 0; r < 4; ++r) {
                const int row = quad * 4 + r;
                float v = s1[tn][r] + b2f(S2l[row * 148 + (row - cl + 127)]);
                if (cl > diff + w * 16 + row) v = -1e30f;
                float p = __expf(v - 4.0f);       // masked -> 0
                s1[tn][r] = p;
                lsum[r] += p;
            }
        }
        // ---- zero P' slab (AFTER shear reads; pad entries must be 0) ----
        #pragma unroll
        for (int i = 0; i < 5; ++i)
            ((uint4*)Ppl)[i * 64 + L] = make_uint4(0, 0, 0, 0);
        // ---- scatter P and sheared P' in MFMA A-layout ----
        #pragma unroll
        for (int tn = 0; tn < 8; ++tn) {
            const int cl = tn * 16 + l15;
            #pragma unroll
            for (int r = 0; r < 4; ++r) {
                const int row = quad * 4 + r;
                const u16 pb = f2b(s1[tn][r]);
                Pl[((cl >> 5) << 9) + (((cl >> 3) & 3) << 7) + (row << 3) + (cl & 7)] = pb;
                const int dc = (w & 1) * 16 + row - cl + 127;   // [0,158]
                Ppl[((dc >> 5) << 9) + (((dc >> 3) & 3) << 7) + (row << 3) + (dc & 7)] = pb;
            }
        }

        // ---- O += P @ V (global Vp fragment stream) ----
        {
            bf8 pa[4];
            #pragma unroll
            for (int kc = 0; kc < 4; ++kc) pa[kc] = ((const bf8*)Pl)[kc * 64 + L];
            const int vb0 = bh * 128 + (s0 >> 5);
            #pragma unroll
            for (int tn = 0; tn < 4; ++tn) {
                #pragma unroll
                for (int kc = 0; kc < 4; ++kc) {
                    const bf8 vf = VPF[(size_t)(vb0 + tn * 32 + kc) * 64 + L];
                    o[tn] = __builtin_amdgcn_mfma_f32_16x16x32_bf16(
                        pa[kc], vf, o[tn], 0, 0, 0);
                }
            }
        }
        // ---- O += P' @ EV (global EVP stream) ----
        {
            bf8 pa[5];
            #pragma unroll
            for (int kc = 0; kc < 5; ++kc) pa[kc] = ((const bf8*)Ppl)[kc * 64 + L];
            const int eb = (diff >> 5) + (w >> 1);
            #pragma unroll
            for (int tn = 0; tn < 4; ++tn) {
                #pragma unroll
                for (int kc = 0; kc < 5; ++kc)
                    o[tn] = __builtin_amdgcn_mfma_f32_16x16x32_bf16(
                        pa[kc], EVPF[(tn * 36 + eb + kc) * 64 + L], o[tn], 0, 0, 0);
            }
        }
    }
    flush(t);
}

// ---------------- combine partial (o, lsum) slots for split tiles, normalize -------
__global__ __launch_bounds__(256) void attn_reduce(const float* __restrict__ po,
                                                   const float* __restrict__ lsp,
                                                   u16* __restrict__ yb) {
    const int gi = blockIdx.x;                    // 0 -> tile 4, i -> tile i+7
    const int t = (gi == 0) ? 4 : (gi + 7);
    const int bh = blockIdx.y, b = bh >> 4, h = bh & 15;
    const int ns = (t == 12) ? 3 : 2;
    const size_t base = (size_t)(bh * 19 + d_SB[t]);
    const float* pob = po + (base << 12);
    const float* lsb = lsp + (base << 6);
    #pragma unroll 1
    for (int i = 0; i < 16; ++i) {
        const int idx = i * 256 + threadIdx.x;
        const int row = idx >> 6, col = idx & 63;
        float acc = 0.f, lacc = 0.f;
        for (int s = 0; s < ns; ++s) {
            acc  += pob[(s << 12) + idx];
            lacc += lsb[(s << 6) + row];
        }
        yb[(size_t)(b * 1024 + t * 64 + row) * 1024 + h * 64 + col] = f2b(acc / lacc);
    }
}

extern "C" void kernel_launch(void* const* d_in, const int* in_sizes, int n_in,
                              void* d_out, int out_size, void* d_ws, size_t ws_size,
                              hipStream_t stream) {
    const float* x      = (const float*)d_in[0];
    const float* w_attn = (const float*)d_in[1];
    const float* w_proj = (const float*)d_in[2];
    const float* embk   = (const float*)d_in[3];
    const float* embv   = (const float*)d_in[4];
    float* out = (float*)d_out;

    u16* wsb   = (u16*)d_ws;
    u16* qkvb  = wsb;                  // 4096*3072            = 12582912
    u16* xb    = qkvb + 12582912;      // 4096*1024            = 4194304
    u16* ymidb = xb;                   // aliases xb (xb dead after gemm1)
    u16* waT   = xb + 4194304;         // 3072*1024            = 3145728
    u16* wpT   = waT + 3145728;        // 1024*1024            = 1048576
    u16* Vt    = wpT + 1048576;        // 64*64*1024           = 4194304
    u16* Kp    = Vt + 4194304;         // 64*64*2*512          = 4194304
    u16* Vp    = Kp + 4194304;         // 64*4*32*512          = 4194304
    u16* EKP   = Vp + 4194304;         // 72*2*512             = 73728
    u16* EVP   = EKP + 73728;          // 4*36*512             = 73728
    float* po  = (float*)(EVP + 73728);// 64*19*4096 f32       = 4980736 f32
    float* lsp = po + 4980736;         // 64*19*64 f32         = 77824 f32

    prep_all<<<dim3(5192), 256, 0, stream>>>(x, embk, embv, w_attn, w_proj,
                                             xb, EKP, EVP, waT, wpT);
    gemm_mfma<u16><<<dim3(24, 32), 256, 0, stream>>>(xb, waT, qkvb, 4096, 3072, 1024);
    prep_vt<<<dim3(16, 64), 256, 0, stream>>>(qkvb, Vt);
    pack_kv<<<dim3(4096), 256, 0, stream>>>(qkvb, Vt, Kp, Vp);
    attn_mfma<<<dim3(18, 64), 256, 0, stream>>>(qkvb, Kp, Vp, EKP, EVP, ymidb, po, lsp);
    attn_reduce<<<dim3(9, 64), 256, 0, stream>>>(po, lsp, ymidb);
    gemm_mfma<float><<<dim3(8, 32), 256, 0, stream>>>(ymidb, wpT, out, 4096, 1024, 1024);
}

// Round 5
// 363.330 us; speedup vs baseline: 1.1666x; 1.0045x over previous
//
#include <hip/hip_runtime.h>
#include <math.h>

typedef unsigned short u16;
typedef short bf8 __attribute__((ext_vector_type(8)));      // 8 bf16 (raw bits)
typedef float f32x4 __attribute__((ext_vector_type(4)));

__device__ __forceinline__ u16 f2b(float f) {
    union { float f; unsigned u; } x; x.f = f;
    return (u16)((x.u + 0x7FFFu + ((x.u >> 16) & 1u)) >> 16);   // RTNE
}
__device__ __forceinline__ float b2f(u16 b) {
    union { unsigned u; float f; } x; x.u = ((unsigned)b) << 16;
    return x.f;
}

__device__ __forceinline__ void async16(const void* g, void* l) {
    __builtin_amdgcn_global_load_lds(
        (const __attribute__((address_space(1))) unsigned int*)g,
        (__attribute__((address_space(3))) unsigned int*)l, 16, 0, 0);
}

__device__ __forceinline__ void cstore(float* p, float v) { *p = v; }
__device__ __forceinline__ void cstore(u16* p, float v) { *p = f2b(v); }

// ---------------- bf16 MFMA GEMM (m97 structure): C[M,N] = A[M,K] @ Bt[N,K]^T ------
template<typename OutT>
__global__ __launch_bounds__(256) void gemm_mfma(const u16* __restrict__ A,
                                                 const u16* __restrict__ Bt,
                                                 OutT* __restrict__ C,
                                                 int M, int N, int K) {
    __shared__ __align__(16) u16 As[128 * 32];
    __shared__ __align__(16) u16 Bs[128 * 32];
    const int tid = threadIdx.x;
    const int w = tid >> 6, L = tid & 63;
    const int l15 = L & 15, quad = L >> 4;
    const int wm = (w >> 1) * 64, wn = (w & 1) * 64;
    const int row0 = blockIdx.y * 128, col0 = blockIdx.x * 128;
    const int laneRow = L >> 2, laneCol8 = (L & 3) * 8;

    f32x4 acc[4][4] = {};

    for (int k0 = 0; k0 < K; k0 += 32) {
        #pragma unroll
        for (int i = 0; i < 2; ++i) {
            const int seg = w * 2 + i;
            const int r = seg * 16 + laneRow;
            async16(&A[(size_t)(row0 + r) * K + k0 + laneCol8], &As[seg * 512 + L * 8]);
        }
        #pragma unroll
        for (int i = 0; i < 2; ++i) {
            const int seg = w * 2 + i;
            const int r = seg * 16 + laneRow;
            async16(&Bt[(size_t)(col0 + r) * K + k0 + laneCol8], &Bs[seg * 512 + L * 8]);
        }
        __syncthreads();
        bf8 a[4], b[4];
        #pragma unroll
        for (int mt = 0; mt < 4; ++mt)
            a[mt] = *(const bf8*)&As[(wm + mt * 16 + l15) * 32 + quad * 8];
        #pragma unroll
        for (int nt = 0; nt < 4; ++nt)
            b[nt] = *(const bf8*)&Bs[(wn + nt * 16 + l15) * 32 + quad * 8];
        #pragma unroll
        for (int mt = 0; mt < 4; ++mt)
            #pragma unroll
            for (int nt = 0; nt < 4; ++nt)
                acc[mt][nt] = __builtin_amdgcn_mfma_f32_16x16x32_bf16(
                    a[mt], b[nt], acc[mt][nt], 0, 0, 0);
        __syncthreads();
    }
    #pragma unroll
    for (int mt = 0; mt < 4; ++mt)
        #pragma unroll
        for (int nt = 0; nt < 4; ++nt) {
            const int col = col0 + wn + nt * 16 + l15;
            #pragma unroll
            for (int r = 0; r < 4; ++r) {
                const int row = row0 + wm + mt * 16 + quad * 4 + r;
                cstore(&C[(size_t)row * N + col], acc[mt][nt][r]);
            }
        }
}

// ---------------- merged prep: x->bf16, EKP/EVP fragment tables, weight transposes --
__global__ __launch_bounds__(256) void prep_all(const float* __restrict__ x,
                                                const float* __restrict__ embk,
                                                const float* __restrict__ embv,
                                                const float* __restrict__ w_attn,
                                                const float* __restrict__ w_proj,
                                                u16* __restrict__ xb,
                                                u16* __restrict__ EKP,
                                                u16* __restrict__ EVP,
                                                u16* __restrict__ waT,
                                                u16* __restrict__ wpT) {
    __shared__ u16 ts[64][65];
    const int bx = blockIdx.x;
    const int tid = threadIdx.x;
    if (bx < 4096) {
        int idx = bx * 256 + tid;
        const float4 v = ((const float4*)x)[idx];
        ((ushort4*)xb)[idx] = make_ushort4(f2b(v.x), f2b(v.y), f2b(v.z), f2b(v.w));
    } else if (bx < 4132) {
        int t = (bx - 4096) * 256 + tid;           // [0, 9216)
        int L = t & 63, kc = (t >> 6) & 1, k16 = t >> 7;
        int l15 = L & 15, quad = L >> 4;
        int row = 1 + k16 * 16 + l15;
        int d = row - 128;
        int cl = d < 0 ? 0 : (d > 1023 ? 1023 : d);
        const float* p = embk + cl * 64 + kc * 32 + quad * 8;
        #pragma unroll
        for (int i = 0; i < 8; ++i) EKP[t * 8 + i] = f2b(p[i]);
    } else if (bx < 4168) {
        int t = (bx - 4132) * 256 + tid;           // [0, 9216)
        int L = t & 63, rest = t >> 6;             // rest = tn*36 + c32
        int c32 = rest % 36, tn = rest / 36;
        int l15 = L & 15, quad = L >> 4;
        #pragma unroll
        for (int i = 0; i < 8; ++i) {
            int c = c32 * 32 + quad * 8 + i;
            int d = c - 127;
            int cl = d < 0 ? 0 : (d > 1023 ? 1023 : d);
            EVP[t * 8 + i] = f2b(embv[cl * 64 + tn * 16 + l15]);
        }
    } else {
        const float* W; u16* WT; int Cc, t;
        if (bx < 4168 + 768) { t = bx - 4168; W = w_attn; WT = waT; Cc = 3072; }
        else                 { t = bx - 4936; W = w_proj; WT = wpT; Cc = 1024; }
        const int nx = Cc >> 6;
        const int c0 = (t % nx) * 64, r0 = (t / nx) * 64;
        for (int i = tid; i < 4096; i += 256) {
            int r = i >> 6, c = i & 63;
            ts[r][c] = f2b(W[(size_t)(r0 + r) * Cc + c0 + c]);
        }
        __syncthreads();
        for (int i = tid; i < 4096; i += 256) {
            int c = i >> 6, r = i & 63;
            WT[(size_t)(c0 + c) * 1024 + r0 + r] = ts[r][c];
        }
    }
}

// ---------------- prep: V^T bf16   Vt[64bh*64 + d][1024 s]  (from bf16 qkv) --------
__global__ __launch_bounds__(256) void prep_vt(const u16* __restrict__ qkvb,
                                               u16* __restrict__ Vt) {
    __shared__ u16 ts[64][65];
    const int tid = threadIdx.x;
    const int s0 = blockIdx.x * 64;
    const int bh = blockIdx.y, b = bh >> 4, h = bh & 15;
    #pragma unroll
    for (int it = 0; it < 4; ++it) {
        int s = it * 16 + (tid >> 4);
        int d4 = (tid & 15) * 4;
        const u16* p = qkvb + (size_t)(b * 1024 + s0 + s) * 3072 + 2048 + h * 64 + d4;
        #pragma unroll
        for (int i = 0; i < 4; ++i) ts[s][d4 + i] = p[i];
    }
    __syncthreads();
    const int d = tid >> 2, si = (tid & 3) * 16;
    __align__(16) u16 buf[16];
    #pragma unroll
    for (int i = 0; i < 16; ++i) buf[i] = ts[si + i][d];
    u16* o = Vt + ((size_t)(bh * 64 + d) << 10) + s0 + si;
    *(uint4*)o       = ((uint4*)buf)[0];
    *(uint4*)(o + 8) = ((uint4*)buf)[1];
}

// ---------------- pack K (pre-scaled by 1/8) and V into B-fragment-linear tables ----
__global__ __launch_bounds__(256) void pack_kv(const u16* __restrict__ qkvb,
                                               const u16* __restrict__ Vt,
                                               u16* __restrict__ Kp,
                                               u16* __restrict__ Vp) {
    const int bx = blockIdx.x;
    if (bx < 2048) {
        int t = bx * 256 + threadIdx.x;            // [0, 524288)
        int L = t & 63, kc = (t >> 6) & 1, s16 = (t >> 7) & 63, bh = t >> 13;
        int l15 = L & 15, quad = L >> 4;
        int b = bh >> 4, h = bh & 15;
        const u16* src = qkvb + (size_t)(b * 1024 + s16 * 16 + l15) * 3072
                       + 1024 + h * 64 + kc * 32 + quad * 8;
        u16* dst = Kp + (size_t)t * 8;
        #pragma unroll
        for (int i = 0; i < 8; ++i) dst[i] = f2b(b2f(src[i]) * 0.125f);
    } else {
        int t = (bx - 2048) * 256 + threadIdx.x;   // [0, 524288)
        int L = t & 63, c32 = (t >> 6) & 31, tn = (t >> 11) & 3, bh = t >> 13;
        int l15 = L & 15, quad = L >> 4;
        const u16* src = Vt + ((size_t)(bh * 64 + tn * 16 + l15) << 10)
                       + c32 * 32 + quad * 8;
        *(uint4*)(Vp + (size_t)t * 8) = *(const uint4*)src;
    }
}

// cumulative chunk counts: tile t owns units [S(t), S(t)+t/2+1); S(16)=72 total.
__device__ const int d_S[17] = {0,1,2,4,6,9,12,16,20,25,30,36,42,49,56,64,72};
// partial-slot base per split tile (tiles 4, 8..15), compact: 19 slots per bh.
// tile:       0  1  2  3  4  5  6  7  8  9 10 11 12 13 14 15
__device__ const int d_SB[16] = {0,0,0,0, 0,0,0,0, 2, 4, 6, 8,10,13,15,17};

// ---------------- MFMA fused attention with RPE: unit-split for 2x wave parallelism -
// Work = 72 equal-cost units per bh (unit = 64 Q-rows x 128 cols chunk).
// grid (18, 64): block k owns units [4k, 4k+4) -> 1152 balanced blocks.
// __launch_bounds__(256) PLAIN — no min-waves arg. R3's (256,4) forced VGPR
// to 64 and spilled ~220MB to HBM; R4's (256,3) still pinned arch-VGPR at 84
// (= accumulator count) with ~50MB spill and LOWER occupancy (scratch caps
// residency). R0/R1 evidence: plain bound -> VGPR 120-124, zero spill, and
// 120<=128 already permits 4 waves/SIMD; LDS 36.9KB*4=147KB fits 4 blocks/CU.
// The hint was never needed — grid size was the limiter and 1152 blocks fix it.
// A tile is finalized inline iff all its units live in ONE block, decided
// structurally: (S(t)>>2) == ((S(t+1)-1)>>2). Split tiles {4, 8..15} flush
// f32 partials (o, lsum) to statically-indexed slots (additive: softmax uses
// fixed exp bias, no running max); attn_reduce sums <=3 slots + normalizes.
// K/V fragments read directly from fragment-linear global tables
// (L2-resident); no barriers anywhere, all LDS per-wave.
__global__ __launch_bounds__(256) void attn_mfma(const u16* __restrict__ qkvb,
                                                 const u16* __restrict__ Kp,
                                                 const u16* __restrict__ Vp,
                                                 const u16* __restrict__ EKP,
                                                 const u16* __restrict__ EVP,
                                                 u16* __restrict__ yb,
                                                 float* __restrict__ po,
                                                 float* __restrict__ lsp) {
    __shared__ __align__(16) u16 slab_[4][4608];   // 36864 B, per-wave overlay

    const int tid = threadIdx.x;
    const int w = tid >> 6, L = tid & 63;
    const int l15 = L & 15, quad = L >> 4;
    const int blk = blockIdx.x;
    const int bh = blockIdx.y, b = bh >> 4, h = bh & 15;
    u16* S2l = slab_[w];
    u16* Pl  = slab_[w];
    u16* Ppl = slab_[w] + 2048;

    const bf8* EKPF = (const bf8*)EKP;
    const bf8* EVPF = (const bf8*)EVP;
    const bf8* KPF  = (const bf8*)Kp;
    const bf8* VPF  = (const bf8*)Vp;

    bf8 qn[2];
    f32x4 o[4];
    float lsum[4];
    int t = -1, t0 = 0;

    auto flush = [&](int tt) {
        float lr[4];
        #pragma unroll
        for (int r = 0; r < 4; ++r) {
            float s = lsum[r];
            s += __shfl_xor(s, 1); s += __shfl_xor(s, 2);
            s += __shfl_xor(s, 4); s += __shfl_xor(s, 8);
            lr[r] = s;
        }
        const bool whole = (d_S[tt] >> 2) == ((d_S[tt + 1] - 1) >> 2);
        if (whole) {           // all units of this tile in this block: finalize
            #pragma unroll
            for (int tn = 0; tn < 4; ++tn) {
                const int col = h * 64 + tn * 16 + l15;
                #pragma unroll
                for (int r = 0; r < 4; ++r) {
                    const int trow = tt * 64 + w * 16 + quad * 4 + r;
                    yb[(size_t)(b * 1024 + trow) * 1024 + col] = f2b(o[tn][r] / lr[r]);
                }
            }
        } else {               // partial: statically-indexed slot
            const int slot = blk - (d_S[tt] >> 2);
            const size_t sidx = (size_t)(bh * 19 + d_SB[tt] + slot);
            float* pob = po + (sidx << 12);
            #pragma unroll
            for (int tn = 0; tn < 4; ++tn)
                #pragma unroll
                for (int r = 0; r < 4; ++r)
                    pob[(w * 16 + quad * 4 + r) * 64 + tn * 16 + l15] = o[tn][r];
            if (l15 == 0) {
                float* lsb = lsp + (sidx << 6);
                #pragma unroll
                for (int r = 0; r < 4; ++r) lsb[w * 16 + quad * 4 + r] = lr[r];
            }
        }
    };

    #pragma unroll 1
    for (int ui = 0; ui < 4; ++ui) {
        const int u = blk * 4 + ui;
        int nt = (t < 0) ? 0 : t;
        while (d_S[nt + 1] <= u) ++nt;
        if (nt != t) {
            if (t >= 0) flush(t);
            t = nt; t0 = t * 64;
            const int trow = t0 + w * 16 + l15;
            const u16* qp = qkvb + (size_t)(b * 1024 + trow) * 3072 + h * 64 + quad * 8;
            qn[0] = *(const bf8*)qp;
            qn[1] = *(const bf8*)(qp + 32);
            #pragma unroll
            for (int tn = 0; tn < 4; ++tn)
                #pragma unroll
                for (int j = 0; j < 4; ++j) o[tn][j] = 0.f;
            #pragma unroll
            for (int r = 0; r < 4; ++r) lsum[r] = 0.f;
        }
        const int c = u - d_S[t];
        const int s0 = c << 7;
        const int diff = t0 - s0;                 // >= 0, multiple of 64

        // ---- S2 = Q @ EK^T (global EKP stream) ----
        f32x4 s2[9] = {};
        {
            const int kb = (diff >> 4) + w;       // k16 base
            #pragma unroll
            for (int j = 0; j < 9; ++j) {
                #pragma unroll
                for (int kc = 0; kc < 2; ++kc)
                    s2[j] = __builtin_amdgcn_mfma_f32_16x16x32_bf16(
                        qn[kc], EKPF[(((kb + j) << 1) + kc) * 64 + L], s2[j], 0, 0, 0);
            }
        }
        #pragma unroll
        for (int j = 0; j < 9; ++j)
            #pragma unroll
            for (int r = 0; r < 4; ++r)
                S2l[(quad * 4 + r) * 148 + j * 16 + l15] = f2b(s2[j][r]);

        // ---- S1 = Q @ (K/8)^T (global Kp fragment stream) ----
        f32x4 s1[8] = {};
        {
            const int kb0 = bh * 64 + (s0 >> 4);
            #pragma unroll
            for (int tn = 0; tn < 8; ++tn) {
                #pragma unroll
                for (int kc = 0; kc < 2; ++kc) {
                    const bf8 kf = KPF[(size_t)((kb0 + tn) * 2 + kc) * 64 + L];
                    s1[tn] = __builtin_amdgcn_mfma_f32_16x16x32_bf16(
                        qn[kc], kf, s1[tn], 0, 0, 0);
                }
            }
        }

        // ---- logits + mask + p = exp(logit - 4); per-lane partial sums ----
        #pragma unroll
        for (int tn = 0; tn < 8; ++tn) {
            const int cl = tn * 16 + l15;
            #pragma unroll
            for (int r = 0; r < 4; ++r) {
                const int row = quad * 4 + r;
                float v = s1[tn][r] + b2f(S2l[row * 148 + (row - cl + 127)]);
                if (cl > diff + w * 16 + row) v = -1e30f;
                float p = __expf(v - 4.0f);       // masked -> 0
                s1[tn][r] = p;
                lsum[r] += p;
            }
        }
        // ---- zero P' slab (AFTER shear reads; pad entries must be 0) ----
        #pragma unroll
        for (int i = 0; i < 5; ++i)
            ((uint4*)Ppl)[i * 64 + L] = make_uint4(0, 0, 0, 0);
        // ---- scatter P and sheared P' in MFMA A-layout ----
        #pragma unroll
        for (int tn = 0; tn < 8; ++tn) {
            const int cl = tn * 16 + l15;
            #pragma unroll
            for (int r = 0; r < 4; ++r) {
                const int row = quad * 4 + r;
                const u16 pb = f2b(s1[tn][r]);
                Pl[((cl >> 5) << 9) + (((cl >> 3) & 3) << 7) + (row << 3) + (cl & 7)] = pb;
                const int dc = (w & 1) * 16 + row - cl + 127;   // [0,158]
                Ppl[((dc >> 5) << 9) + (((dc >> 3) & 3) << 7) + (row << 3) + (dc & 7)] = pb;
            }
        }

        // ---- O += P @ V (global Vp fragment stream) ----
        {
            bf8 pa[4];
            #pragma unroll
            for (int kc = 0; kc < 4; ++kc) pa[kc] = ((const bf8*)Pl)[kc * 64 + L];
            const int vb0 = bh * 128 + (s0 >> 5);
            #pragma unroll
            for (int tn = 0; tn < 4; ++tn) {
                #pragma unroll
                for (int kc = 0; kc < 4; ++kc) {
                    const bf8 vf = VPF[(size_t)(vb0 + tn * 32 + kc) * 64 + L];
                    o[tn] = __builtin_amdgcn_mfma_f32_16x16x32_bf16(
                        pa[kc], vf, o[tn], 0, 0, 0);
                }
            }
        }
        // ---- O += P' @ EV (global EVP stream) ----
        {
            bf8 pa[5];
            #pragma unroll
            for (int kc = 0; kc < 5; ++kc) pa[kc] = ((const bf8*)Ppl)[kc * 64 + L];
            const int eb = (diff >> 5) + (w >> 1);
            #pragma unroll
            for (int tn = 0; tn < 4; ++tn) {
                #pragma unroll
                for (int kc = 0; kc < 5; ++kc)
                    o[tn] = __builtin_amdgcn_mfma_f32_16x16x32_bf16(
                        pa[kc], EVPF[(tn * 36 + eb + kc) * 64 + L], o[tn], 0, 0, 0);
            }
        }
    }
    flush(t);
}

// ---------------- combine partial (o, lsum) slots for split tiles, normalize -------
__global__ __launch_bounds__(256) void attn_reduce(const float* __restrict__ po,
                                                   const float* __restrict__ lsp,
                                                   u16* __restrict__ yb) {
    const int gi = blockIdx.x;                    // 0 -> tile 4, i -> tile i+7
    const int t = (gi == 0) ? 4 : (gi + 7);
    const int bh = blockIdx.y, b = bh >> 4, h = bh & 15;
    const int ns = (t == 12) ? 3 : 2;
    const size_t base = (size_t)(bh * 19 + d_SB[t]);
    const float* pob = po + (base << 12);
    const float* lsb = lsp + (base << 6);
    #pragma unroll 1
    for (int i = 0; i < 16; ++i) {
        const int idx = i * 256 + threadIdx.x;
        const int row = idx >> 6, col = idx & 63;
        float acc = 0.f, lacc = 0.f;
        for (int s = 0; s < ns; ++s) {
            acc  += pob[(s << 12) + idx];
            lacc += lsb[(s << 6) + row];
        }
        yb[(size_t)(b * 1024 + t * 64 + row) * 1024 + h * 64 + col] = f2b(acc / lacc);
    }
}

extern "C" void kernel_launch(void* const* d_in, const int* in_sizes, int n_in,
                              void* d_out, int out_size, void* d_ws, size_t ws_size,
                              hipStream_t stream) {
    const float* x      = (const float*)d_in[0];
    const float* w_attn = (const float*)d_in[1];
    const float* w_proj = (const float*)d_in[2];
    const float* embk   = (const float*)d_in[3];
    const float* embv   = (const float*)d_in[4];
    float* out = (float*)d_out;

    u16* wsb   = (u16*)d_ws;
    u16* qkvb  = wsb;                  // 4096*3072            = 12582912
    u16* xb    = qkvb + 12582912;      // 4096*1024            = 4194304
    u16* ymidb = xb;                   // aliases xb (xb dead after gemm1)
    u16* waT   = xb + 4194304;         // 3072*1024            = 3145728
    u16* wpT   = waT + 3145728;        // 1024*1024            = 1048576
    u16* Vt    = wpT + 1048576;        // 64*64*1024           = 4194304
    u16* Kp    = Vt + 4194304;         // 64*64*2*512          = 4194304
    u16* Vp    = Kp + 4194304;         // 64*4*32*512          = 4194304
    u16* EKP   = Vp + 4194304;         // 72*2*512             = 73728
    u16* EVP   = EKP + 73728;          // 4*36*512             = 73728
    float* po  = (float*)(EVP + 73728);// 64*19*4096 f32       = 4980736 f32
    float* lsp = po + 4980736;         // 64*19*64 f32         = 77824 f32

    prep_all<<<dim3(5192), 256, 0, stream>>>(x, embk, embv, w_attn, w_proj,
                                             xb, EKP, EVP, waT, wpT);
    gemm_mfma<u16><<<dim3(24, 32), 256, 0, stream>>>(xb, waT, qkvb, 4096, 3072, 1024);
    prep_vt<<<dim3(16, 64), 256, 0, stream>>>(qkvb, Vt);
    pack_kv<<<dim3(4096), 256, 0, stream>>>(qkvb, Vt, Kp, Vp);
    attn_mfma<<<dim3(18, 64), 256, 0, stream>>>(qkvb, Kp, Vp, EKP, EVP, ymidb, po, lsp);
    attn_reduce<<<dim3(9, 64), 256, 0, stream>>>(po, lsp, ymidb);
    gemm_mfma<float><<<dim3(8, 32), 256, 0, stream>>>(ymidb, wpT, out, 4096, 1024, 1024);
}

// Round 6
// 285.542 us; speedup vs baseline: 1.4844x; 1.2724x over previous
//
#include <hip/hip_runtime.h>
#include <math.h>

typedef unsigned short u16;
typedef short bf8 __attribute__((ext_vector_type(8)));      // 8 bf16 (raw bits)
typedef float f32x4 __attribute__((ext_vector_type(4)));

__device__ __forceinline__ u16 f2b(float f) {
    union { float f; unsigned u; } x; x.f = f;
    return (u16)((x.u + 0x7FFFu + ((x.u >> 16) & 1u)) >> 16);   // RTNE
}
__device__ __forceinline__ float b2f(u16 b) {
    union { unsigned u; float f; } x; x.u = ((unsigned)b) << 16;
    return x.f;
}

__device__ __forceinline__ void async16(const void* g, void* l) {
    __builtin_amdgcn_global_load_lds(
        (const __attribute__((address_space(1))) unsigned int*)g,
        (__attribute__((address_space(3))) unsigned int*)l, 16, 0, 0);
}

__device__ __forceinline__ void cstore(float* p, float v) { *p = v; }
__device__ __forceinline__ void cstore(u16* p, float v) { *p = f2b(v); }

// ---------------- bf16 MFMA GEMM (m97 structure): C[M,N] = A[M,K] @ Bt[N,K]^T ------
template<typename OutT>
__global__ __launch_bounds__(256) void gemm_mfma(const u16* __restrict__ A,
                                                 const u16* __restrict__ Bt,
                                                 OutT* __restrict__ C,
                                                 int M, int N, int K) {
    __shared__ __align__(16) u16 As[128 * 32];
    __shared__ __align__(16) u16 Bs[128 * 32];
    const int tid = threadIdx.x;
    const int w = tid >> 6, L = tid & 63;
    const int l15 = L & 15, quad = L >> 4;
    const int wm = (w >> 1) * 64, wn = (w & 1) * 64;
    const int row0 = blockIdx.y * 128, col0 = blockIdx.x * 128;
    const int laneRow = L >> 2, laneCol8 = (L & 3) * 8;

    f32x4 acc[4][4] = {};

    for (int k0 = 0; k0 < K; k0 += 32) {
        #pragma unroll
        for (int i = 0; i < 2; ++i) {
            const int seg = w * 2 + i;
            const int r = seg * 16 + laneRow;
            async16(&A[(size_t)(row0 + r) * K + k0 + laneCol8], &As[seg * 512 + L * 8]);
        }
        #pragma unroll
        for (int i = 0; i < 2; ++i) {
            const int seg = w * 2 + i;
            const int r = seg * 16 + laneRow;
            async16(&Bt[(size_t)(col0 + r) * K + k0 + laneCol8], &Bs[seg * 512 + L * 8]);
        }
        __syncthreads();
        bf8 a[4], b[4];
        #pragma unroll
        for (int mt = 0; mt < 4; ++mt)
            a[mt] = *(const bf8*)&As[(wm + mt * 16 + l15) * 32 + quad * 8];
        #pragma unroll
        for (int nt = 0; nt < 4; ++nt)
            b[nt] = *(const bf8*)&Bs[(wn + nt * 16 + l15) * 32 + quad * 8];
        #pragma unroll
        for (int mt = 0; mt < 4; ++mt)
            #pragma unroll
            for (int nt = 0; nt < 4; ++nt)
                acc[mt][nt] = __builtin_amdgcn_mfma_f32_16x16x32_bf16(
                    a[mt], b[nt], acc[mt][nt], 0, 0, 0);
        __syncthreads();
    }
    #pragma unroll
    for (int mt = 0; mt < 4; ++mt)
        #pragma unroll
        for (int nt = 0; nt < 4; ++nt) {
            const int col = col0 + wn + nt * 16 + l15;
            #pragma unroll
            for (int r = 0; r < 4; ++r) {
                const int row = row0 + wm + mt * 16 + quad * 4 + r;
                cstore(&C[(size_t)row * N + col], acc[mt][nt][r]);
            }
        }
}

// ---------------- merged prep: x->bf16, EKP/EVP fragment tables, weight transposes --
__global__ __launch_bounds__(256) void prep_all(const float* __restrict__ x,
                                                const float* __restrict__ embk,
                                                const float* __restrict__ embv,
                                                const float* __restrict__ w_attn,
                                                const float* __restrict__ w_proj,
                                                u16* __restrict__ xb,
                                                u16* __restrict__ EKP,
                                                u16* __restrict__ EVP,
                                                u16* __restrict__ waT,
                                                u16* __restrict__ wpT) {
    __shared__ u16 ts[64][65];
    const int bx = blockIdx.x;
    const int tid = threadIdx.x;
    if (bx < 4096) {
        int idx = bx * 256 + tid;
        const float4 v = ((const float4*)x)[idx];
        ((ushort4*)xb)[idx] = make_ushort4(f2b(v.x), f2b(v.y), f2b(v.z), f2b(v.w));
    } else if (bx < 4132) {
        int t = (bx - 4096) * 256 + tid;           // [0, 9216)
        int L = t & 63, kc = (t >> 6) & 1, k16 = t >> 7;
        int l15 = L & 15, quad = L >> 4;
        int row = 1 + k16 * 16 + l15;
        int d = row - 128;
        int cl = d < 0 ? 0 : (d > 1023 ? 1023 : d);
        const float* p = embk + cl * 64 + kc * 32 + quad * 8;
        #pragma unroll
        for (int i = 0; i < 8; ++i) EKP[t * 8 + i] = f2b(p[i]);
    } else if (bx < 4168) {
        int t = (bx - 4132) * 256 + tid;           // [0, 9216)
        int L = t & 63, rest = t >> 6;             // rest = tn*36 + c32
        int c32 = rest % 36, tn = rest / 36;
        int l15 = L & 15, quad = L >> 4;
        #pragma unroll
        for (int i = 0; i < 8; ++i) {
            int c = c32 * 32 + quad * 8 + i;
            int d = c - 127;
            int cl = d < 0 ? 0 : (d > 1023 ? 1023 : d);
            EVP[t * 8 + i] = f2b(embv[cl * 64 + tn * 16 + l15]);
        }
    } else {
        const float* W; u16* WT; int Cc, t;
        if (bx < 4168 + 768) { t = bx - 4168; W = w_attn; WT = waT; Cc = 3072; }
        else                 { t = bx - 4936; W = w_proj; WT = wpT; Cc = 1024; }
        const int nx = Cc >> 6;
        const int c0 = (t % nx) * 64, r0 = (t / nx) * 64;
        for (int i = tid; i < 4096; i += 256) {
            int r = i >> 6, c = i & 63;
            ts[r][c] = f2b(W[(size_t)(r0 + r) * Cc + c0 + c]);
        }
        __syncthreads();
        for (int i = tid; i < 4096; i += 256) {
            int c = i >> 6, r = i & 63;
            WT[(size_t)(c0 + c) * 1024 + r0 + r] = ts[r][c];
        }
    }
}

// ---------------- prep: V^T bf16   Vt[64bh*64 + d][1024 s]  (from bf16 qkv) --------
__global__ __launch_bounds__(256) void prep_vt(const u16* __restrict__ qkvb,
                                               u16* __restrict__ Vt) {
    __shared__ u16 ts[64][65];
    const int tid = threadIdx.x;
    const int s0 = blockIdx.x * 64;
    const int bh = blockIdx.y, b = bh >> 4, h = bh & 15;
    #pragma unroll
    for (int it = 0; it < 4; ++it) {
        int s = it * 16 + (tid >> 4);
        int d4 = (tid & 15) * 4;
        const u16* p = qkvb + (size_t)(b * 1024 + s0 + s) * 3072 + 2048 + h * 64 + d4;
        #pragma unroll
        for (int i = 0; i < 4; ++i) ts[s][d4 + i] = p[i];
    }
    __syncthreads();
    const int d = tid >> 2, si = (tid & 3) * 16;
    __align__(16) u16 buf[16];
    #pragma unroll
    for (int i = 0; i < 16; ++i) buf[i] = ts[si + i][d];
    u16* o = Vt + ((size_t)(bh * 64 + d) << 10) + s0 + si;
    *(uint4*)o       = ((uint4*)buf)[0];
    *(uint4*)(o + 8) = ((uint4*)buf)[1];
}

// ---------------- pack K (pre-scaled by 1/8) and V into B-fragment-linear tables ----
__global__ __launch_bounds__(256) void pack_kv(const u16* __restrict__ qkvb,
                                               const u16* __restrict__ Vt,
                                               u16* __restrict__ Kp,
                                               u16* __restrict__ Vp) {
    const int bx = blockIdx.x;
    if (bx < 2048) {
        int t = bx * 256 + threadIdx.x;            // [0, 524288)
        int L = t & 63, kc = (t >> 6) & 1, s16 = (t >> 7) & 63, bh = t >> 13;
        int l15 = L & 15, quad = L >> 4;
        int b = bh >> 4, h = bh & 15;
        const u16* src = qkvb + (size_t)(b * 1024 + s16 * 16 + l15) * 3072
                       + 1024 + h * 64 + kc * 32 + quad * 8;
        u16* dst = Kp + (size_t)t * 8;
        #pragma unroll
        for (int i = 0; i < 8; ++i) dst[i] = f2b(b2f(src[i]) * 0.125f);
    } else {
        int t = (bx - 2048) * 256 + threadIdx.x;   // [0, 524288)
        int L = t & 63, c32 = (t >> 6) & 31, tn = (t >> 11) & 3, bh = t >> 13;
        int l15 = L & 15, quad = L >> 4;
        const u16* src = Vt + ((size_t)(bh * 64 + tn * 16 + l15) << 10)
                       + c32 * 32 + quad * 8;
        *(uint4*)(Vp + (size_t)t * 8) = *(const uint4*)src;
    }
}

// cumulative chunk counts: tile t owns units [S(t), S(t)+t/2+1); S(16)=72 total.
__device__ const int d_S[17] = {0,1,2,4,6,9,12,16,20,25,30,36,42,49,56,64,72};
// partial-slot base per split tile (tiles 4, 8..15), compact: 19 slots per bh.
// tile:       0  1  2  3  4  5  6  7  8  9 10 11 12 13 14 15
__device__ const int d_SB[16] = {0,0,0,0, 0,0,0,0, 2, 4, 6, 8,10,13,15,17};

// ---------------- MFMA fused attention with RPE: R0 staged pipeline x unit-split ----
// grid (18, 64): block k owns units [4k,4k+4) of the canonical (tile,chunk)
// order (unit = 64 Q-rows x 128 cols) -> 1152 balanced blocks. Inner loop is
// R0's proven 2-barrier DMA pipeline: barrier1 (prior KVs reads retired) ->
// issue 32KB K/V global_load_lds -> S2 EKP-stream MFMAs cover DMA latency ->
// barrier2 (vmcnt drain) -> S1/PV consume K/V via ds_read_b128. Direct-global
// K/V (R1/R5) loses 25-60% to exposed L2 latency — do not remove staging.
// LDS shrunk to fit 3 blocks/CU (12 waves/CU, 1.5x R0): per-wave slab is ONE
// 2560-u16 overlay; uses are time-disjoint and same-wave DS is in-order:
// S2l[0,2368) -> logits consume -> P[0,2048) scatter -> pa ds_reads (get old
// data; reads can't be passed by later writes) -> zero+scatter P'[0,2560) ->
// P'EV. f2b(s1) recomputed in the P' pass (cheaper than 16 VGPRs of cache).
// Plain __launch_bounds__(256): ANY min-waves hint forces spills (R3: 220MB,
// R4: 50MB scratch). VGPR ~128 <= 170 keeps 3 waves/SIMD for 3 blocks/CU.
// Tile finalized inline iff whole in one block ((S(t)>>2)==((S(t+1)-1)>>2));
// split tiles {4,8..15} flush additive f32 partials to static slots;
// attn_reduce combines <=3 slots + normalizes.
__global__ __launch_bounds__(256) void attn_mfma(const u16* __restrict__ qkvb,
                                                 const u16* __restrict__ Kp,
                                                 const u16* __restrict__ Vp,
                                                 const u16* __restrict__ EKP,
                                                 const u16* __restrict__ EVP,
                                                 u16* __restrict__ yb,
                                                 float* __restrict__ po,
                                                 float* __restrict__ lsp) {
    __shared__ __align__(16) u16 slab_[4][2560];   // 20480 B, per-wave overlay
    __shared__ __align__(16) u16 KVs[16384];       // 32768 B: K [0..8192), V [8192..)

    const int tid = threadIdx.x;
    const int w = tid >> 6, L = tid & 63;
    const int l15 = L & 15, quad = L >> 4;
    const int blk = blockIdx.x;
    const int bh = blockIdx.y, b = bh >> 4, h = bh & 15;
    u16* S2l = slab_[w];
    u16* Pl  = slab_[w];
    u16* Ppl = slab_[w];

    const bf8* EKPF = (const bf8*)EKP;
    const bf8* EVPF = (const bf8*)EVP;

    bf8 qn[2];
    f32x4 o[4];
    float lsum[4];
    int t = -1, t0 = 0;

    auto flush = [&](int tt) {
        float lr[4];
        #pragma unroll
        for (int r = 0; r < 4; ++r) {
            float s = lsum[r];
            s += __shfl_xor(s, 1); s += __shfl_xor(s, 2);
            s += __shfl_xor(s, 4); s += __shfl_xor(s, 8);
            lr[r] = s;
        }
        const bool whole = (d_S[tt] >> 2) == ((d_S[tt + 1] - 1) >> 2);
        if (whole) {           // all units of this tile in this block: finalize
            #pragma unroll
            for (int tn = 0; tn < 4; ++tn) {
                const int col = h * 64 + tn * 16 + l15;
                #pragma unroll
                for (int r = 0; r < 4; ++r) {
                    const int trow = tt * 64 + w * 16 + quad * 4 + r;
                    yb[(size_t)(b * 1024 + trow) * 1024 + col] = f2b(o[tn][r] / lr[r]);
                }
            }
        } else {               // partial: statically-indexed slot
            const int slot = blk - (d_S[tt] >> 2);
            const size_t sidx = (size_t)(bh * 19 + d_SB[tt] + slot);
            float* pob = po + (sidx << 12);
            #pragma unroll
            for (int tn = 0; tn < 4; ++tn)
                #pragma unroll
                for (int r = 0; r < 4; ++r)
                    pob[(w * 16 + quad * 4 + r) * 64 + tn * 16 + l15] = o[tn][r];
            if (l15 == 0) {
                float* lsb = lsp + (sidx << 6);
                #pragma unroll
                for (int r = 0; r < 4; ++r) lsb[w * 16 + quad * 4 + r] = lr[r];
            }
        }
    };

    #pragma unroll 1
    for (int ui = 0; ui < 4; ++ui) {
        const int u = blk * 4 + ui;
        int nt = (t < 0) ? 0 : t;
        while (d_S[nt + 1] <= u) ++nt;
        if (nt != t) {
            if (t >= 0) flush(t);
            t = nt; t0 = t * 64;
            const int trow = t0 + w * 16 + l15;
            const u16* qp = qkvb + (size_t)(b * 1024 + trow) * 3072 + h * 64 + quad * 8;
            qn[0] = *(const bf8*)qp;
            qn[1] = *(const bf8*)(qp + 32);
            #pragma unroll
            for (int tn = 0; tn < 4; ++tn)
                #pragma unroll
                for (int j = 0; j < 4; ++j) o[tn][j] = 0.f;
            #pragma unroll
            for (int r = 0; r < 4; ++r) lsum[r] = 0.f;
        }
        const int c = u - d_S[t];
        const int s0 = c << 7;
        const int diff = t0 - s0;                 // >= 0, multiple of 64

        __syncthreads();    // prior unit's KVs reads retired

        // ---- issue K/V chunk DMA (16 KB K contiguous; V = 4 runs of 4 KB) ----
        {
            const size_t kbase = ((size_t)(bh * 64 + (s0 >> 4)) << 1) * 512;
            #pragma unroll
            for (int i = 0; i < 4; ++i)
                async16(Kp + kbase + (i * 256 + tid) * 8, &KVs[(i * 256 + tid) * 8]);
            const int vb = bh * 128 + (s0 >> 5);
            #pragma unroll
            for (int i = 0; i < 4; ++i)
                async16(Vp + ((size_t)(vb + i * 32) * 512 + tid * 8),
                        &KVs[8192 + i * 2048 + tid * 8]);
        }

        // ---- S2 = Q @ EK^T (global EKP stream; overlaps the DMA) ----
        f32x4 s2[9] = {};
        {
            const int kb = (diff >> 4) + w;       // k16 base
            #pragma unroll
            for (int j = 0; j < 9; ++j) {
                #pragma unroll
                for (int kc = 0; kc < 2; ++kc)
                    s2[j] = __builtin_amdgcn_mfma_f32_16x16x32_bf16(
                        qn[kc], EKPF[(((kb + j) << 1) + kc) * 64 + L], s2[j], 0, 0, 0);
            }
        }
        #pragma unroll
        for (int j = 0; j < 9; ++j)
            #pragma unroll
            for (int r = 0; r < 4; ++r)
                S2l[(quad * 4 + r) * 148 + j * 16 + l15] = f2b(s2[j][r]);

        __syncthreads();    // KVs DMA complete (vmcnt drain)

        // ---- S1 = Q @ (K/8)^T from LDS ----
        f32x4 s1[8] = {};
        #pragma unroll
        for (int tn = 0; tn < 8; ++tn) {
            #pragma unroll
            for (int kc = 0; kc < 2; ++kc) {
                const bf8 kf = *(const bf8*)&KVs[((tn << 1) + kc) * 512 + L * 8];
                s1[tn] = __builtin_amdgcn_mfma_f32_16x16x32_bf16(
                    qn[kc], kf, s1[tn], 0, 0, 0);
            }
        }

        // ---- logits + mask + p = exp(logit - 4); per-lane partial sums ----
        #pragma unroll
        for (int tn = 0; tn < 8; ++tn) {
            const int cl = tn * 16 + l15;
            #pragma unroll
            for (int r = 0; r < 4; ++r) {
                const int row = quad * 4 + r;
                float v = s1[tn][r] + b2f(S2l[row * 148 + (row - cl + 127)]);
                if (cl > diff + w * 16 + row) v = -1e30f;
                float p = __expf(v - 4.0f);       // masked -> 0
                s1[tn][r] = p;
                lsum[r] += p;
            }
        }

        // ---- scatter P in MFMA A-layout (clobbers dead S2l region) ----
        #pragma unroll
        for (int tn = 0; tn < 8; ++tn) {
            const int cl = tn * 16 + l15;
            #pragma unroll
            for (int r = 0; r < 4; ++r) {
                const int row = quad * 4 + r;
                Pl[((cl >> 5) << 9) + (((cl >> 3) & 3) << 7) + (row << 3) + (cl & 7)]
                    = f2b(s1[tn][r]);
            }
        }
        // ---- read P fragments (in-order DS: reads precede overlay writes) ----
        bf8 pa[4];
        #pragma unroll
        for (int kc = 0; kc < 4; ++kc) pa[kc] = ((const bf8*)Pl)[kc * 64 + L];

        // ---- rebuild overlay as sheared P' (zero pads, then scatter) ----
        #pragma unroll
        for (int i = 0; i < 5; ++i)
            ((uint4*)Ppl)[i * 64 + L] = make_uint4(0, 0, 0, 0);
        #pragma unroll
        for (int tn = 0; tn < 8; ++tn) {
            const int cl = tn * 16 + l15;
            #pragma unroll
            for (int r = 0; r < 4; ++r) {
                const int row = quad * 4 + r;
                const int dc = (w & 1) * 16 + row - cl + 127;   // [0,158]
                Ppl[((dc >> 5) << 9) + (((dc >> 3) & 3) << 7) + (row << 3) + (dc & 7)]
                    = f2b(s1[tn][r]);
            }
        }

        // ---- O += P @ V (V frags from LDS) ----
        {
            #pragma unroll
            for (int tn = 0; tn < 4; ++tn) {
                #pragma unroll
                for (int kc = 0; kc < 4; ++kc) {
                    const bf8 vf = *(const bf8*)&KVs[8192 + (tn * 4 + kc) * 512 + L * 8];
                    o[tn] = __builtin_amdgcn_mfma_f32_16x16x32_bf16(
                        pa[kc], vf, o[tn], 0, 0, 0);
                }
            }
        }
        // ---- O += P' @ EV (global EVP stream) ----
        {
            bf8 pb[5];
            #pragma unroll
            for (int kc = 0; kc < 5; ++kc) pb[kc] = ((const bf8*)Ppl)[kc * 64 + L];
            const int eb = (diff >> 5) + (w >> 1);
            #pragma unroll
            for (int tn = 0; tn < 4; ++tn) {
                #pragma unroll
                for (int kc = 0; kc < 5; ++kc)
                    o[tn] = __builtin_amdgcn_mfma_f32_16x16x32_bf16(
                        pb[kc], EVPF[(tn * 36 + eb + kc) * 64 + L], o[tn], 0, 0, 0);
            }
        }
    }
    flush(t);
}

// ---------------- combine partial (o, lsum) slots for split tiles, normalize -------
__global__ __launch_bounds__(256) void attn_reduce(const float* __restrict__ po,
                                                   const float* __restrict__ lsp,
                                                   u16* __restrict__ yb) {
    const int gi = blockIdx.x;                    // 0 -> tile 4, i -> tile i+7
    const int t = (gi == 0) ? 4 : (gi + 7);
    const int bh = blockIdx.y, b = bh >> 4, h = bh & 15;
    const int ns = (t == 12) ? 3 : 2;
    const size_t base = (size_t)(bh * 19 + d_SB[t]);
    const float* pob = po + (base << 12);
    const float* lsb = lsp + (base << 6);
    #pragma unroll 1
    for (int i = 0; i < 16; ++i) {
        const int idx = i * 256 + threadIdx.x;
        const int row = idx >> 6, col = idx & 63;
        float acc = 0.f, lacc = 0.f;
        for (int s = 0; s < ns; ++s) {
            acc  += pob[(s << 12) + idx];
            lacc += lsb[(s << 6) + row];
        }
        yb[(size_t)(b * 1024 + t * 64 + row) * 1024 + h * 64 + col] = f2b(acc / lacc);
    }
}

extern "C" void kernel_launch(void* const* d_in, const int* in_sizes, int n_in,
                              void* d_out, int out_size, void* d_ws, size_t ws_size,
                              hipStream_t stream) {
    const float* x      = (const float*)d_in[0];
    const float* w_attn = (const float*)d_in[1];
    const float* w_proj = (const float*)d_in[2];
    const float* embk   = (const float*)d_in[3];
    const float* embv   = (const float*)d_in[4];
    float* out = (float*)d_out;

    u16* wsb   = (u16*)d_ws;
    u16* qkvb  = wsb;                  // 4096*3072            = 12582912
    u16* xb    = qkvb + 12582912;      // 4096*1024            = 4194304
    u16* ymidb = xb;                   // aliases xb (xb dead after gemm1)
    u16* waT   = xb + 4194304;         // 3072*1024            = 3145728
    u16* wpT   = waT + 3145728;        // 1024*1024            = 1048576
    u16* Vt    = wpT + 1048576;        // 64*64*1024           = 4194304
    u16* Kp    = Vt + 4194304;         // 64*64*2*512          = 4194304
    u16* Vp    = Kp + 4194304;         // 64*4*32*512          = 4194304
    u16* EKP   = Vp + 4194304;         // 72*2*512             = 73728
    u16* EVP   = EKP + 73728;          // 4*36*512             = 73728
    float* po  = (float*)(EVP + 73728);// 64*19*4096 f32       = 4980736 f32
    float* lsp = po + 4980736;         // 64*19*64 f32         = 77824 f32

    prep_all<<<dim3(5192), 256, 0, stream>>>(x, embk, embv, w_attn, w_proj,
                                             xb, EKP, EVP, waT, wpT);
    gemm_mfma<u16><<<dim3(24, 32), 256, 0, stream>>>(xb, waT, qkvb, 4096, 3072, 1024);
    prep_vt<<<dim3(16, 64), 256, 0, stream>>>(qkvb, Vt);
    pack_kv<<<dim3(4096), 256, 0, stream>>>(qkvb, Vt, Kp, Vp);
    attn_mfma<<<dim3(18, 64), 256, 0, stream>>>(qkvb, Kp, Vp, EKP, EVP, ymidb, po, lsp);
    attn_reduce<<<dim3(9, 64), 256, 0, stream>>>(po, lsp, ymidb);
    gemm_mfma<float><<<dim3(8, 32), 256, 0, stream>>>(ymidb, wpT, out, 4096, 1024, 1024);
}

// Round 7
// 274.496 us; speedup vs baseline: 1.5441x; 1.0402x over previous
//
#include <hip/hip_runtime.h>
#include <math.h>

typedef unsigned short u16;
typedef short bf8 __attribute__((ext_vector_type(8)));      // 8 bf16 (raw bits)
typedef float f32x4 __attribute__((ext_vector_type(4)));

__device__ __forceinline__ u16 f2b(float f) {
    union { float f; unsigned u; } x; x.f = f;
    return (u16)((x.u + 0x7FFFu + ((x.u >> 16) & 1u)) >> 16);   // RTNE
}
__device__ __forceinline__ float b2f(u16 b) {
    union { unsigned u; float f; } x; x.u = ((unsigned)b) << 16;
    return x.f;
}

__device__ __forceinline__ void async16(const void* g, void* l) {
    __builtin_amdgcn_global_load_lds(
        (const __attribute__((address_space(1))) unsigned int*)g,
        (__attribute__((address_space(3))) unsigned int*)l, 16, 0, 0);
}

__device__ __forceinline__ void cstore(float* p, float v) { *p = v; }
__device__ __forceinline__ void cstore(u16* p, float v) { *p = f2b(v); }

// ---------------- bf16 MFMA GEMM (m97 structure): C[M,N] = A[M,K] @ Bt[N,K]^T ------
template<typename OutT>
__global__ __launch_bounds__(256) void gemm_mfma(const u16* __restrict__ A,
                                                 const u16* __restrict__ Bt,
                                                 OutT* __restrict__ C,
                                                 int M, int N, int K) {
    __shared__ __align__(16) u16 As[128 * 32];
    __shared__ __align__(16) u16 Bs[128 * 32];
    const int tid = threadIdx.x;
    const int w = tid >> 6, L = tid & 63;
    const int l15 = L & 15, quad = L >> 4;
    const int wm = (w >> 1) * 64, wn = (w & 1) * 64;
    const int row0 = blockIdx.y * 128, col0 = blockIdx.x * 128;
    const int laneRow = L >> 2, laneCol8 = (L & 3) * 8;

    f32x4 acc[4][4] = {};

    for (int k0 = 0; k0 < K; k0 += 32) {
        #pragma unroll
        for (int i = 0; i < 2; ++i) {
            const int seg = w * 2 + i;
            const int r = seg * 16 + laneRow;
            async16(&A[(size_t)(row0 + r) * K + k0 + laneCol8], &As[seg * 512 + L * 8]);
        }
        #pragma unroll
        for (int i = 0; i < 2; ++i) {
            const int seg = w * 2 + i;
            const int r = seg * 16 + laneRow;
            async16(&Bt[(size_t)(col0 + r) * K + k0 + laneCol8], &Bs[seg * 512 + L * 8]);
        }
        __syncthreads();
        bf8 a[4], b[4];
        #pragma unroll
        for (int mt = 0; mt < 4; ++mt)
            a[mt] = *(const bf8*)&As[(wm + mt * 16 + l15) * 32 + quad * 8];
        #pragma unroll
        for (int nt = 0; nt < 4; ++nt)
            b[nt] = *(const bf8*)&Bs[(wn + nt * 16 + l15) * 32 + quad * 8];
        #pragma unroll
        for (int mt = 0; mt < 4; ++mt)
            #pragma unroll
            for (int nt = 0; nt < 4; ++nt)
                acc[mt][nt] = __builtin_amdgcn_mfma_f32_16x16x32_bf16(
                    a[mt], b[nt], acc[mt][nt], 0, 0, 0);
        __syncthreads();
    }
    #pragma unroll
    for (int mt = 0; mt < 4; ++mt)
        #pragma unroll
        for (int nt = 0; nt < 4; ++nt) {
            const int col = col0 + wn + nt * 16 + l15;
            #pragma unroll
            for (int r = 0; r < 4; ++r) {
                const int row = row0 + wm + mt * 16 + quad * 4 + r;
                cstore(&C[(size_t)row * N + col], acc[mt][nt][r]);
            }
        }
}

// ---------------- 64x128-tile variant: doubles block count for small-N GEMMs -------
// gemm2 at 128x128 had grid 256 = 1 block/CU = 1 wave/SIMD (zero latency
// hiding). 64(M)x128(N) tile -> grid (8,64) = 512 blocks, 2/CU. Wave w owns a
// 32x64 sub-tile: acc[2][4], 8 MFMA per K-step. Same m97 staging pattern.
template<typename OutT>
__global__ __launch_bounds__(256) void gemm_mfma64(const u16* __restrict__ A,
                                                   const u16* __restrict__ Bt,
                                                   OutT* __restrict__ C,
                                                   int M, int N, int K) {
    __shared__ __align__(16) u16 As[64 * 32];
    __shared__ __align__(16) u16 Bs[128 * 32];
    const int tid = threadIdx.x;
    const int w = tid >> 6, L = tid & 63;
    const int l15 = L & 15, quad = L >> 4;
    const int wm = (w >> 1) * 32, wn = (w & 1) * 64;
    const int row0 = blockIdx.y * 64, col0 = blockIdx.x * 128;
    const int laneRow = L >> 2, laneCol8 = (L & 3) * 8;

    f32x4 acc[2][4] = {};

    for (int k0 = 0; k0 < K; k0 += 32) {
        {   // A: 64x32 = 256 chunks, one per thread (seg = w)
            const int r = w * 16 + laneRow;
            async16(&A[(size_t)(row0 + r) * K + k0 + laneCol8], &As[w * 512 + L * 8]);
        }
        #pragma unroll
        for (int i = 0; i < 2; ++i) {   // B: 128x32 = 512 chunks, two per thread
            const int seg = w * 2 + i;
            const int r = seg * 16 + laneRow;
            async16(&Bt[(size_t)(col0 + r) * K + k0 + laneCol8], &Bs[seg * 512 + L * 8]);
        }
        __syncthreads();
        bf8 a[2], b[4];
        #pragma unroll
        for (int mt = 0; mt < 2; ++mt)
            a[mt] = *(const bf8*)&As[(wm + mt * 16 + l15) * 32 + quad * 8];
        #pragma unroll
        for (int nt = 0; nt < 4; ++nt)
            b[nt] = *(const bf8*)&Bs[(wn + nt * 16 + l15) * 32 + quad * 8];
        #pragma unroll
        for (int mt = 0; mt < 2; ++mt)
            #pragma unroll
            for (int nt = 0; nt < 4; ++nt)
                acc[mt][nt] = __builtin_amdgcn_mfma_f32_16x16x32_bf16(
                    a[mt], b[nt], acc[mt][nt], 0, 0, 0);
        __syncthreads();
    }
    #pragma unroll
    for (int mt = 0; mt < 2; ++mt)
        #pragma unroll
        for (int nt = 0; nt < 4; ++nt) {
            const int col = col0 + wn + nt * 16 + l15;
            #pragma unroll
            for (int r = 0; r < 4; ++r) {
                const int row = row0 + wm + mt * 16 + quad * 4 + r;
                cstore(&C[(size_t)row * N + col], acc[mt][nt][r]);
            }
        }
}

// ---------------- merged prep: x->bf16, EKP/EVP fragment tables, weight transposes --
__global__ __launch_bounds__(256) void prep_all(const float* __restrict__ x,
                                                const float* __restrict__ embk,
                                                const float* __restrict__ embv,
                                                const float* __restrict__ w_attn,
                                                const float* __restrict__ w_proj,
                                                u16* __restrict__ xb,
                                                u16* __restrict__ EKP,
                                                u16* __restrict__ EVP,
                                                u16* __restrict__ waT,
                                                u16* __restrict__ wpT) {
    __shared__ u16 ts[64][65];
    const int bx = blockIdx.x;
    const int tid = threadIdx.x;
    if (bx < 4096) {
        int idx = bx * 256 + tid;
        const float4 v = ((const float4*)x)[idx];
        ((ushort4*)xb)[idx] = make_ushort4(f2b(v.x), f2b(v.y), f2b(v.z), f2b(v.w));
    } else if (bx < 4132) {
        int t = (bx - 4096) * 256 + tid;           // [0, 9216)
        int L = t & 63, kc = (t >> 6) & 1, k16 = t >> 7;
        int l15 = L & 15, quad = L >> 4;
        int row = 1 + k16 * 16 + l15;
        int d = row - 128;
        int cl = d < 0 ? 0 : (d > 1023 ? 1023 : d);
        const float* p = embk + cl * 64 + kc * 32 + quad * 8;
        #pragma unroll
        for (int i = 0; i < 8; ++i) EKP[t * 8 + i] = f2b(p[i]);
    } else if (bx < 4168) {
        int t = (bx - 4132) * 256 + tid;           // [0, 9216)
        int L = t & 63, rest = t >> 6;             // rest = tn*36 + c32
        int c32 = rest % 36, tn = rest / 36;
        int l15 = L & 15, quad = L >> 4;
        #pragma unroll
        for (int i = 0; i < 8; ++i) {
            int c = c32 * 32 + quad * 8 + i;
            int d = c - 127;
            int cl = d < 0 ? 0 : (d > 1023 ? 1023 : d);
            EVP[t * 8 + i] = f2b(embv[cl * 64 + tn * 16 + l15]);
        }
    } else {
        const float* W; u16* WT; int Cc, t;
        if (bx < 4168 + 768) { t = bx - 4168; W = w_attn; WT = waT; Cc = 3072; }
        else                 { t = bx - 4936; W = w_proj; WT = wpT; Cc = 1024; }
        const int nx = Cc >> 6;
        const int c0 = (t % nx) * 64, r0 = (t / nx) * 64;
        for (int i = tid; i < 4096; i += 256) {
            int r = i >> 6, c = i & 63;
            ts[r][c] = f2b(W[(size_t)(r0 + r) * Cc + c0 + c]);
        }
        __syncthreads();
        for (int i = tid; i < 4096; i += 256) {
            int c = i >> 6, r = i & 63;
            WT[(size_t)(c0 + c) * 1024 + r0 + r] = ts[r][c];
        }
    }
}

// ---------------- pack K (pre-scaled 1/8) + V into fragment-linear tables ----------
// V path FUSED (replaces prep_vt + old pack_kv V-half): reads V straight from
// qkvb, transposes a 32(s)x64(d) tile in LDS, emits Vp fragments. Kills the
// 8MB Vt intermediate (16MB of HBM/L2 round-trip) and one kernel launch.
// Vp fragment t = bh*8192 + tn*2048 + c32*64 + L holds
// V[b, c32*32 + quad*8 + i, h, tn*16 + l15], i=0..7  (verified == old chain).
__global__ __launch_bounds__(256) void pack_kv2(const u16* __restrict__ qkvb,
                                                u16* __restrict__ Kp,
                                                u16* __restrict__ Vp) {
    const int bx = blockIdx.x;
    if (bx < 2048) {
        int t = bx * 256 + threadIdx.x;            // [0, 524288)
        int L = t & 63, kc = (t >> 6) & 1, s16 = (t >> 7) & 63, bh = t >> 13;
        int l15 = L & 15, quad = L >> 4;
        int b = bh >> 4, h = bh & 15;
        const u16* src = qkvb + (size_t)(b * 1024 + s16 * 16 + l15) * 3072
                       + 1024 + h * 64 + kc * 32 + quad * 8;
        u16* dst = Kp + (size_t)t * 8;
        #pragma unroll
        for (int i = 0; i < 8; ++i) dst[i] = f2b(b2f(src[i]) * 0.125f);
    } else {
        __shared__ __align__(16) u16 ts[64][40];   // [d][s_local], 40-pad => 16B rows
        const int tid = threadIdx.x;
        const int bxx = bx - 2048;                 // [0, 2048)
        const int bh = bxx >> 5, c32 = bxx & 31;
        const int b = bh >> 4, h = bh & 15;
        {   // load V[b, c32*32 + s_local, h, 0..64] and transpose into ts
            const int sl = tid >> 3, d8 = (tid & 7) * 8;
            const u16* p = qkvb + (size_t)(b * 1024 + c32 * 32 + sl) * 3072
                         + 2048 + h * 64 + d8;
            uint4 v = *(const uint4*)p;
            const u16* e = (const u16*)&v;
            #pragma unroll
            for (int i = 0; i < 8; ++i) ts[d8 + i][sl] = e[i];
        }
        __syncthreads();
        const int tn = tid >> 6, L = tid & 63;
        const int l15 = L & 15, quad = L >> 4;
        const uint4 frag = *(const uint4*)&ts[tn * 16 + l15][quad * 8];
        *(uint4*)(Vp + ((size_t)(bh * 8192 + tn * 2048 + c32 * 64 + L)) * 8) = frag;
    }
}

// cumulative chunk counts: tile t owns units [S(t), S(t)+t/2+1); S(16)=72 total.
__device__ const int d_S[17] = {0,1,2,4,6,9,12,16,20,25,30,36,42,49,56,64,72};
// partial-slot base per split tile (tiles 4, 8..15), compact: 19 slots per bh.
// tile:       0  1  2  3  4  5  6  7  8  9 10 11 12 13 14 15
__device__ const int d_SB[16] = {0,0,0,0, 0,0,0,0, 2, 4, 6, 8,10,13,15,17};

// ---------------- MFMA fused attention with RPE: R0 staged pipeline x unit-split ----
// grid (18, 64): block k owns units [4k,4k+4) of the canonical (tile,chunk)
// order (unit = 64 Q-rows x 128 cols) -> 1152 balanced blocks. Inner loop is
// R0's proven 2-barrier DMA pipeline. Direct-global K/V (R1/R5) loses 25-60%
// to exposed L2 latency — do not remove staging. Per-wave slab is ONE 2560-u16
// overlay (time-disjoint uses; same-wave DS is in-order). Plain
// __launch_bounds__(256): ANY min-waves hint forces spills (R3/R4 evidence).
// Structure verified at 115.7us (R6) — further occupancy/barrier knobs were
// all neutral-or-worse across R1-R6; treat as the practical floor of this
// decomposition.
__global__ __launch_bounds__(256) void attn_mfma(const u16* __restrict__ qkvb,
                                                 const u16* __restrict__ Kp,
                                                 const u16* __restrict__ Vp,
                                                 const u16* __restrict__ EKP,
                                                 const u16* __restrict__ EVP,
                                                 u16* __restrict__ yb,
                                                 float* __restrict__ po,
                                                 float* __restrict__ lsp) {
    __shared__ __align__(16) u16 slab_[4][2560];   // 20480 B, per-wave overlay
    __shared__ __align__(16) u16 KVs[16384];       // 32768 B: K [0..8192), V [8192..)

    const int tid = threadIdx.x;
    const int w = tid >> 6, L = tid & 63;
    const int l15 = L & 15, quad = L >> 4;
    const int blk = blockIdx.x;
    const int bh = blockIdx.y, b = bh >> 4, h = bh & 15;
    u16* S2l = slab_[w];
    u16* Pl  = slab_[w];
    u16* Ppl = slab_[w];

    const bf8* EKPF = (const bf8*)EKP;
    const bf8* EVPF = (const bf8*)EVP;

    bf8 qn[2];
    f32x4 o[4];
    float lsum[4];
    int t = -1, t0 = 0;

    auto flush = [&](int tt) {
        float lr[4];
        #pragma unroll
        for (int r = 0; r < 4; ++r) {
            float s = lsum[r];
            s += __shfl_xor(s, 1); s += __shfl_xor(s, 2);
            s += __shfl_xor(s, 4); s += __shfl_xor(s, 8);
            lr[r] = s;
        }
        const bool whole = (d_S[tt] >> 2) == ((d_S[tt + 1] - 1) >> 2);
        if (whole) {           // all units of this tile in this block: finalize
            #pragma unroll
            for (int tn = 0; tn < 4; ++tn) {
                const int col = h * 64 + tn * 16 + l15;
                #pragma unroll
                for (int r = 0; r < 4; ++r) {
                    const int trow = tt * 64 + w * 16 + quad * 4 + r;
                    yb[(size_t)(b * 1024 + trow) * 1024 + col] = f2b(o[tn][r] / lr[r]);
                }
            }
        } else {               // partial: statically-indexed slot
            const int slot = blk - (d_S[tt] >> 2);
            const size_t sidx = (size_t)(bh * 19 + d_SB[tt] + slot);
            float* pob = po + (sidx << 12);
            #pragma unroll
            for (int tn = 0; tn < 4; ++tn)
                #pragma unroll
                for (int r = 0; r < 4; ++r)
                    pob[(w * 16 + quad * 4 + r) * 64 + tn * 16 + l15] = o[tn][r];
            if (l15 == 0) {
                float* lsb = lsp + (sidx << 6);
                #pragma unroll
                for (int r = 0; r < 4; ++r) lsb[w * 16 + quad * 4 + r] = lr[r];
            }
        }
    };

    #pragma unroll 1
    for (int ui = 0; ui < 4; ++ui) {
        const int u = blk * 4 + ui;
        int nt = (t < 0) ? 0 : t;
        while (d_S[nt + 1] <= u) ++nt;
        if (nt != t) {
            if (t >= 0) flush(t);
            t = nt; t0 = t * 64;
            const int trow = t0 + w * 16 + l15;
            const u16* qp = qkvb + (size_t)(b * 1024 + trow) * 3072 + h * 64 + quad * 8;
            qn[0] = *(const bf8*)qp;
            qn[1] = *(const bf8*)(qp + 32);
            #pragma unroll
            for (int tn = 0; tn < 4; ++tn)
                #pragma unroll
                for (int j = 0; j < 4; ++j) o[tn][j] = 0.f;
            #pragma unroll
            for (int r = 0; r < 4; ++r) lsum[r] = 0.f;
        }
        const int c = u - d_S[t];
        const int s0 = c << 7;
        const int diff = t0 - s0;                 // >= 0, multiple of 64

        __syncthreads();    // prior unit's KVs reads retired

        // ---- issue K/V chunk DMA (16 KB K contiguous; V = 4 runs of 4 KB) ----
        {
            const size_t kbase = ((size_t)(bh * 64 + (s0 >> 4)) << 1) * 512;
            #pragma unroll
            for (int i = 0; i < 4; ++i)
                async16(Kp + kbase + (i * 256 + tid) * 8, &KVs[(i * 256 + tid) * 8]);
            const int vb = bh * 128 + (s0 >> 5);
            #pragma unroll
            for (int i = 0; i < 4; ++i)
                async16(Vp + ((size_t)(vb + i * 32) * 512 + tid * 8),
                        &KVs[8192 + i * 2048 + tid * 8]);
        }

        // ---- S2 = Q @ EK^T (global EKP stream; overlaps the DMA) ----
        f32x4 s2[9] = {};
        {
            const int kb = (diff >> 4) + w;       // k16 base
            #pragma unroll
            for (int j = 0; j < 9; ++j) {
                #pragma unroll
                for (int kc = 0; kc < 2; ++kc)
                    s2[j] = __builtin_amdgcn_mfma_f32_16x16x32_bf16(
                        qn[kc], EKPF[(((kb + j) << 1) + kc) * 64 + L], s2[j], 0, 0, 0);
            }
        }
        #pragma unroll
        for (int j = 0; j < 9; ++j)
            #pragma unroll
            for (int r = 0; r < 4; ++r)
                S2l[(quad * 4 + r) * 148 + j * 16 + l15] = f2b(s2[j][r]);

        __syncthreads();    // KVs DMA complete (vmcnt drain)

        // ---- S1 = Q @ (K/8)^T from LDS ----
        f32x4 s1[8] = {};
        #pragma unroll
        for (int tn = 0; tn < 8; ++tn) {
            #pragma unroll
            for (int kc = 0; kc < 2; ++kc) {
                const bf8 kf = *(const bf8*)&KVs[((tn << 1) + kc) * 512 + L * 8];
                s1[tn] = __builtin_amdgcn_mfma_f32_16x16x32_bf16(
                    qn[kc], kf, s1[tn], 0, 0, 0);
            }
        }

        // ---- logits + mask + p = exp(logit - 4); per-lane partial sums ----
        #pragma unroll
        for (int tn = 0; tn < 8; ++tn) {
            const int cl = tn * 16 + l15;
            #pragma unroll
            for (int r = 0; r < 4; ++r) {
                const int row = quad * 4 + r;
                float v = s1[tn][r] + b2f(S2l[row * 148 + (row - cl + 127)]);
                if (cl > diff + w * 16 + row) v = -1e30f;
                float p = __expf(v - 4.0f);       // masked -> 0
                s1[tn][r] = p;
                lsum[r] += p;
            }
        }

        // ---- scatter P in MFMA A-layout (clobbers dead S2l region) ----
        #pragma unroll
        for (int tn = 0; tn < 8; ++tn) {
            const int cl = tn * 16 + l15;
            #pragma unroll
            for (int r = 0; r < 4; ++r) {
                const int row = quad * 4 + r;
                Pl[((cl >> 5) << 9) + (((cl >> 3) & 3) << 7) + (row << 3) + (cl & 7)]
                    = f2b(s1[tn][r]);
            }
        }
        // ---- read P fragments (in-order DS: reads precede overlay writes) ----
        bf8 pa[4];
        #pragma unroll
        for (int kc = 0; kc < 4; ++kc) pa[kc] = ((const bf8*)Pl)[kc * 64 + L];

        // ---- rebuild overlay as sheared P' (zero pads, then scatter) ----
        #pragma unroll
        for (int i = 0; i < 5; ++i)
            ((uint4*)Ppl)[i * 64 + L] = make_uint4(0, 0, 0, 0);
        #pragma unroll
        for (int tn = 0; tn < 8; ++tn) {
            const int cl = tn * 16 + l15;
            #pragma unroll
            for (int r = 0; r < 4; ++r) {
                const int row = quad * 4 + r;
                const int dc = (w & 1) * 16 + row - cl + 127;   // [0,158]
                Ppl[((dc >> 5) << 9) + (((dc >> 3) & 3) << 7) + (row << 3) + (dc & 7)]
                    = f2b(s1[tn][r]);
            }
        }

        // ---- O += P @ V (V frags from LDS) ----
        {
            #pragma unroll
            for (int tn = 0; tn < 4; ++tn) {
                #pragma unroll
                for (int kc = 0; kc < 4; ++kc) {
                    const bf8 vf = *(const bf8*)&KVs[8192 + (tn * 4 + kc) * 512 + L * 8];
                    o[tn] = __builtin_amdgcn_mfma_f32_16x16x32_bf16(
                        pa[kc], vf, o[tn], 0, 0, 0);
                }
            }
        }
        // ---- O += P' @ EV (global EVP stream) ----
        {
            bf8 pb[5];
            #pragma unroll
            for (int kc = 0; kc < 5; ++kc) pb[kc] = ((const bf8*)Ppl)[kc * 64 + L];
            const int eb = (diff >> 5) + (w >> 1);
            #pragma unroll
            for (int tn = 0; tn < 4; ++tn) {
                #pragma unroll
                for (int kc = 0; kc < 5; ++kc)
                    o[tn] = __builtin_amdgcn_mfma_f32_16x16x32_bf16(
                        pb[kc], EVPF[(tn * 36 + eb + kc) * 64 + L], o[tn], 0, 0, 0);
            }
        }
    }
    flush(t);
}

// ---------------- combine partial (o, lsum) slots for split tiles, normalize -------
__global__ __launch_bounds__(256) void attn_reduce(const float* __restrict__ po,
                                                   const float* __restrict__ lsp,
                                                   u16* __restrict__ yb) {
    const int gi = blockIdx.x;                    // 0 -> tile 4, i -> tile i+7
    const int t = (gi == 0) ? 4 : (gi + 7);
    const int bh = blockIdx.y, b = bh >> 4, h = bh & 15;
    const int ns = (t == 12) ? 3 : 2;
    const size_t base = (size_t)(bh * 19 + d_SB[t]);
    const float* pob = po + (base << 12);
    const float* lsb = lsp + (base << 6);
    #pragma unroll 1
    for (int i = 0; i < 16; ++i) {
        const int idx = i * 256 + threadIdx.x;
        const int row = idx >> 6, col = idx & 63;
        float acc = 0.f, lacc = 0.f;
        for (int s = 0; s < ns; ++s) {
            acc  += pob[(s << 12) + idx];
            lacc += lsb[(s << 6) + row];
        }
        yb[(size_t)(b * 1024 + t * 64 + row) * 1024 + h * 64 + col] = f2b(acc / lacc);
    }
}

extern "C" void kernel_launch(void* const* d_in, const int* in_sizes, int n_in,
                              void* d_out, int out_size, void* d_ws, size_t ws_size,
                              hipStream_t stream) {
    const float* x      = (const float*)d_in[0];
    const float* w_attn = (const float*)d_in[1];
    const float* w_proj = (const float*)d_in[2];
    const float* embk   = (const float*)d_in[3];
    const float* embv   = (const float*)d_in[4];
    float* out = (float*)d_out;

    u16* wsb   = (u16*)d_ws;
    u16* qkvb  = wsb;                  // 4096*3072            = 12582912
    u16* xb    = qkvb + 12582912;      // 4096*1024            = 4194304
    u16* ymidb = xb;                   // aliases xb (xb dead after gemm1)
    u16* waT   = xb + 4194304;         // 3072*1024            = 3145728
    u16* wpT   = waT + 3145728;        // 1024*1024            = 1048576
    u16* Vt    = wpT + 1048576;        // (slot unused now; layout kept stable)
    u16* Kp    = Vt + 4194304;         // 64*64*2*512          = 4194304
    u16* Vp    = Kp + 4194304;         // 64*4*32*512          = 4194304
    u16* EKP   = Vp + 4194304;         // 72*2*512             = 73728
    u16* EVP   = EKP + 73728;          // 4*36*512             = 73728
    float* po  = (float*)(EVP + 73728);// 64*19*4096 f32       = 4980736 f32
    float* lsp = po + 4980736;         // 64*19*64 f32         = 77824 f32

    prep_all<<<dim3(5192), 256, 0, stream>>>(x, embk, embv, w_attn, w_proj,
                                             xb, EKP, EVP, waT, wpT);
    gemm_mfma<u16><<<dim3(24, 32), 256, 0, stream>>>(xb, waT, qkvb, 4096, 3072, 1024);
    pack_kv2<<<dim3(4096), 256, 0, stream>>>(qkvb, Kp, Vp);
    attn_mfma<<<dim3(18, 64), 256, 0, stream>>>(qkvb, Kp, Vp, EKP, EVP, ymidb, po, lsp);
    attn_reduce<<<dim3(9, 64), 256, 0, stream>>>(po, lsp, ymidb);
    gemm_mfma64<float><<<dim3(8, 64), 256, 0, stream>>>(ymidb, wpT, out, 4096, 1024, 1024);
}

// Round 8
// 238.860 us; speedup vs baseline: 1.7745x; 1.1492x over previous
//
#include <hip/hip_runtime.h>
#include <math.h>

typedef unsigned short u16;
typedef short bf8 __attribute__((ext_vector_type(8)));      // 8 bf16 (raw bits)
typedef float f32x4 __attribute__((ext_vector_type(4)));

__device__ __forceinline__ u16 f2b(float f) {
    union { float f; unsigned u; } x; x.f = f;
    return (u16)((x.u + 0x7FFFu + ((x.u >> 16) & 1u)) >> 16);   // RTNE
}
__device__ __forceinline__ float b2f(u16 b) {
    union { unsigned u; float f; } x; x.u = ((unsigned)b) << 16;
    return x.f;
}

__device__ __forceinline__ void async16(const void* g, void* l) {
    __builtin_amdgcn_global_load_lds(
        (const __attribute__((address_space(1))) unsigned int*)g,
        (__attribute__((address_space(3))) unsigned int*)l, 16, 0, 0);
}

__device__ __forceinline__ void cstore(float* p, float v) { *p = v; }
__device__ __forceinline__ void cstore(u16* p, float v) { *p = f2b(v); }

// ---------------- bf16 MFMA GEMM (m97 structure): C[M,N] = A[M,K] @ Bt[N,K]^T ------
template<typename OutT>
__global__ __launch_bounds__(256) void gemm_mfma(const u16* __restrict__ A,
                                                 const u16* __restrict__ Bt,
                                                 OutT* __restrict__ C,
                                                 int M, int N, int K) {
    __shared__ __align__(16) u16 As[128 * 32];
    __shared__ __align__(16) u16 Bs[128 * 32];
    const int tid = threadIdx.x;
    const int w = tid >> 6, L = tid & 63;
    const int l15 = L & 15, quad = L >> 4;
    const int wm = (w >> 1) * 64, wn = (w & 1) * 64;
    const int row0 = blockIdx.y * 128, col0 = blockIdx.x * 128;
    const int laneRow = L >> 2, laneCol8 = (L & 3) * 8;

    f32x4 acc[4][4] = {};

    for (int k0 = 0; k0 < K; k0 += 32) {
        #pragma unroll
        for (int i = 0; i < 2; ++i) {
            const int seg = w * 2 + i;
            const int r = seg * 16 + laneRow;
            async16(&A[(size_t)(row0 + r) * K + k0 + laneCol8], &As[seg * 512 + L * 8]);
        }
        #pragma unroll
        for (int i = 0; i < 2; ++i) {
            const int seg = w * 2 + i;
            const int r = seg * 16 + laneRow;
            async16(&Bt[(size_t)(col0 + r) * K + k0 + laneCol8], &Bs[seg * 512 + L * 8]);
        }
        __syncthreads();
        bf8 a[4], b[4];
        #pragma unroll
        for (int mt = 0; mt < 4; ++mt)
            a[mt] = *(const bf8*)&As[(wm + mt * 16 + l15) * 32 + quad * 8];
        #pragma unroll
        for (int nt = 0; nt < 4; ++nt)
            b[nt] = *(const bf8*)&Bs[(wn + nt * 16 + l15) * 32 + quad * 8];
        #pragma unroll
        for (int mt = 0; mt < 4; ++mt)
            #pragma unroll
            for (int nt = 0; nt < 4; ++nt)
                acc[mt][nt] = __builtin_amdgcn_mfma_f32_16x16x32_bf16(
                    a[mt], b[nt], acc[mt][nt], 0, 0, 0);
        __syncthreads();
    }
    #pragma unroll
    for (int mt = 0; mt < 4; ++mt)
        #pragma unroll
        for (int nt = 0; nt < 4; ++nt) {
            const int col = col0 + wn + nt * 16 + l15;
            #pragma unroll
            for (int r = 0; r < 4; ++r) {
                const int row = row0 + wm + mt * 16 + quad * 4 + r;
                cstore(&C[(size_t)row * N + col], acc[mt][nt][r]);
            }
        }
}

// ---------------- 64x128-tile variant: doubles block count for small-N GEMMs -------
// gemm2 at 128x128 had grid 256 = 1 block/CU = 1 wave/SIMD (zero latency
// hiding). 64(M)x128(N) tile -> grid (8,64) = 512 blocks, 2/CU. Wave w owns a
// 32x64 sub-tile: acc[2][4], 8 MFMA per K-step. Same m97 staging pattern.
template<typename OutT>
__global__ __launch_bounds__(256) void gemm_mfma64(const u16* __restrict__ A,
                                                   const u16* __restrict__ Bt,
                                                   OutT* __restrict__ C,
                                                   int M, int N, int K) {
    __shared__ __align__(16) u16 As[64 * 32];
    __shared__ __align__(16) u16 Bs[128 * 32];
    const int tid = threadIdx.x;
    const int w = tid >> 6, L = tid & 63;
    const int l15 = L & 15, quad = L >> 4;
    const int wm = (w >> 1) * 32, wn = (w & 1) * 64;
    const int row0 = blockIdx.y * 64, col0 = blockIdx.x * 128;
    const int laneRow = L >> 2, laneCol8 = (L & 3) * 8;

    f32x4 acc[2][4] = {};

    for (int k0 = 0; k0 < K; k0 += 32) {
        {   // A: 64x32 = 256 chunks, one per thread (seg = w)
            const int r = w * 16 + laneRow;
            async16(&A[(size_t)(row0 + r) * K + k0 + laneCol8], &As[w * 512 + L * 8]);
        }
        #pragma unroll
        for (int i = 0; i < 2; ++i) {   // B: 128x32 = 512 chunks, two per thread
            const int seg = w * 2 + i;
            const int r = seg * 16 + laneRow;
            async16(&Bt[(size_t)(col0 + r) * K + k0 + laneCol8], &Bs[seg * 512 + L * 8]);
        }
        __syncthreads();
        bf8 a[2], b[4];
        #pragma unroll
        for (int mt = 0; mt < 2; ++mt)
            a[mt] = *(const bf8*)&As[(wm + mt * 16 + l15) * 32 + quad * 8];
        #pragma unroll
        for (int nt = 0; nt < 4; ++nt)
            b[nt] = *(const bf8*)&Bs[(wn + nt * 16 + l15) * 32 + quad * 8];
        #pragma unroll
        for (int mt = 0; mt < 2; ++mt)
            #pragma unroll
            for (int nt = 0; nt < 4; ++nt)
                acc[mt][nt] = __builtin_amdgcn_mfma_f32_16x16x32_bf16(
                    a[mt], b[nt], acc[mt][nt], 0, 0, 0);
        __syncthreads();
    }
    #pragma unroll
    for (int mt = 0; mt < 2; ++mt)
        #pragma unroll
        for (int nt = 0; nt < 4; ++nt) {
            const int col = col0 + wn + nt * 16 + l15;
            #pragma unroll
            for (int r = 0; r < 4; ++r) {
                const int row = row0 + wm + mt * 16 + quad * 4 + r;
                cstore(&C[(size_t)row * N + col], acc[mt][nt][r]);
            }
        }
}

// ---------------- merged prep: x->bf16, EKP/EVP fragment tables, weight transposes --
__global__ __launch_bounds__(256) void prep_all(const float* __restrict__ x,
                                                const float* __restrict__ embk,
                                                const float* __restrict__ embv,
                                                const float* __restrict__ w_attn,
                                                const float* __restrict__ w_proj,
                                                u16* __restrict__ xb,
                                                u16* __restrict__ EKP,
                                                u16* __restrict__ EVP,
                                                u16* __restrict__ waT,
                                                u16* __restrict__ wpT) {
    __shared__ u16 ts[64][65];
    const int bx = blockIdx.x;
    const int tid = threadIdx.x;
    if (bx < 4096) {
        int idx = bx * 256 + tid;
        const float4 v = ((const float4*)x)[idx];
        ((ushort4*)xb)[idx] = make_ushort4(f2b(v.x), f2b(v.y), f2b(v.z), f2b(v.w));
    } else if (bx < 4132) {
        int t = (bx - 4096) * 256 + tid;           // [0, 9216)
        int L = t & 63, kc = (t >> 6) & 1, k16 = t >> 7;
        int l15 = L & 15, quad = L >> 4;
        int row = 1 + k16 * 16 + l15;
        int d = row - 128;
        int cl = d < 0 ? 0 : (d > 1023 ? 1023 : d);
        const float* p = embk + cl * 64 + kc * 32 + quad * 8;
        #pragma unroll
        for (int i = 0; i < 8; ++i) EKP[t * 8 + i] = f2b(p[i]);
    } else if (bx < 4168) {
        int t = (bx - 4132) * 256 + tid;           // [0, 9216)
        int L = t & 63, rest = t >> 6;             // rest = tn*36 + c32
        int c32 = rest % 36, tn = rest / 36;
        int l15 = L & 15, quad = L >> 4;
        #pragma unroll
        for (int i = 0; i < 8; ++i) {
            int c = c32 * 32 + quad * 8 + i;
            int d = c - 127;
            int cl = d < 0 ? 0 : (d > 1023 ? 1023 : d);
            EVP[t * 8 + i] = f2b(embv[cl * 64 + tn * 16 + l15]);
        }
    } else {
        const float* W; u16* WT; int Cc, t;
        if (bx < 4168 + 768) { t = bx - 4168; W = w_attn; WT = waT; Cc = 3072; }
        else                 { t = bx - 4936; W = w_proj; WT = wpT; Cc = 1024; }
        const int nx = Cc >> 6;
        const int c0 = (t % nx) * 64, r0 = (t / nx) * 64;
        for (int i = tid; i < 4096; i += 256) {
            int r = i >> 6, c = i & 63;
            ts[r][c] = f2b(W[(size_t)(r0 + r) * Cc + c0 + c]);
        }
        __syncthreads();
        for (int i = tid; i < 4096; i += 256) {
            int c = i >> 6, r = i & 63;
            WT[(size_t)(c0 + c) * 1024 + r0 + r] = ts[r][c];
        }
    }
}

// ---------------- pack K (pre-scaled 1/8) + V into fragment-linear tables ----------
// V path fused (R7, verified): reads V straight from qkvb, transposes a
// 32(s)x64(d) tile in LDS, emits Vp fragments identical to the old chain.
__global__ __launch_bounds__(256) void pack_kv2(const u16* __restrict__ qkvb,
                                                u16* __restrict__ Kp,
                                                u16* __restrict__ Vp) {
    const int bx = blockIdx.x;
    if (bx < 2048) {
        int t = bx * 256 + threadIdx.x;            // [0, 524288)
        int L = t & 63, kc = (t >> 6) & 1, s16 = (t >> 7) & 63, bh = t >> 13;
        int l15 = L & 15, quad = L >> 4;
        int b = bh >> 4, h = bh & 15;
        const u16* src = qkvb + (size_t)(b * 1024 + s16 * 16 + l15) * 3072
                       + 1024 + h * 64 + kc * 32 + quad * 8;
        u16* dst = Kp + (size_t)t * 8;
        #pragma unroll
        for (int i = 0; i < 8; ++i) dst[i] = f2b(b2f(src[i]) * 0.125f);
    } else {
        __shared__ __align__(16) u16 ts[64][40];   // [d][s_local], 40-pad => 16B rows
        const int tid = threadIdx.x;
        const int bxx = bx - 2048;                 // [0, 2048)
        const int bh = bxx >> 5, c32 = bxx & 31;
        const int b = bh >> 4, h = bh & 15;
        {   // load V[b, c32*32 + s_local, h, 0..64] and transpose into ts
            const int sl = tid >> 3, d8 = (tid & 7) * 8;
            const u16* p = qkvb + (size_t)(b * 1024 + c32 * 32 + sl) * 3072
                         + 2048 + h * 64 + d8;
            uint4 v = *(const uint4*)p;
            const u16* e = (const u16*)&v;
            #pragma unroll
            for (int i = 0; i < 8; ++i) ts[d8 + i][sl] = e[i];
        }
        __syncthreads();
        const int tn = tid >> 6, L = tid & 63;
        const int l15 = L & 15, quad = L >> 4;
        const uint4 frag = *(const uint4*)&ts[tn * 16 + l15][quad * 8];
        *(uint4*)(Vp + ((size_t)(bh * 8192 + tn * 2048 + c32 * 64 + L)) * 8) = frag;
    }
}

// cumulative chunk counts: tile t owns units [S(t), S(t)+t/2+1); S(16)=72 total.
__device__ const int d_S[17] = {0,1,2,4,6,9,12,16,20,25,30,36,42,49,56,64,72};
// partial-slot base per split tile (tiles 4, 8..15), compact: 19 slots per bh.
// tile:       0  1  2  3  4  5  6  7  8  9 10 11 12 13 14 15
__device__ const int d_SB[16] = {0,0,0,0, 0,0,0,0, 2, 4, 6, 8,10,13,15,17};

// ---------------- MFMA fused attention with RPE: split-barrier staged pipeline -----
// grid (18, 64), unit-split as R6/R7 (verified). NEW this round (T4/T5):
//   bar1 = __syncthreads (drain ~free: everything already consumed)
//   issue K DMA -> S2 EKP stream covers K latency -> [sched_barrier] ->
//   issue V DMA LAST -> asm vmcnt(4) waits ONLY the 4 older K-DMAs/thread
//   (V stays in flight) -> raw s_barrier -> S1 consumes K while V's latency
//   hides under softmax+scatter -> bar3 = __syncthreads (vmcnt(0) drain is
//   ~free, V landed long ago) -> PV + P'EV.
// Old code's bar2 was a full vmcnt(0) drain of all 32KB K+V — the V half was
// pure exposed stall. s_setprio(1) wraps MFMA clusters (attn +4-7%, m191).
// Hazards checked: K-region (per-wave vmcnt(4) precedes rendezvous), V-region
// (full drain at bar3), reuse (bar1 rendezvous), slab per-wave in-order,
// control flow block-uniform. sched_barrier(0) after each barrier/waitcnt
// fences load hoisting (rule #18).
__global__ __launch_bounds__(256) void attn_mfma(const u16* __restrict__ qkvb,
                                                 const u16* __restrict__ Kp,
                                                 const u16* __restrict__ Vp,
                                                 const u16* __restrict__ EKP,
                                                 const u16* __restrict__ EVP,
                                                 u16* __restrict__ yb,
                                                 float* __restrict__ po,
                                                 float* __restrict__ lsp) {
    __shared__ __align__(16) u16 slab_[4][2560];   // 20480 B, per-wave overlay
    __shared__ __align__(16) u16 KVs[16384];       // 32768 B: K [0..8192), V [8192..)

    const int tid = threadIdx.x;
    const int w = tid >> 6, L = tid & 63;
    const int l15 = L & 15, quad = L >> 4;
    const int blk = blockIdx.x;
    const int bh = blockIdx.y, b = bh >> 4, h = bh & 15;
    u16* S2l = slab_[w];
    u16* Pl  = slab_[w];
    u16* Ppl = slab_[w];

    const bf8* EKPF = (const bf8*)EKP;
    const bf8* EVPF = (const bf8*)EVP;

    bf8 qn[2];
    f32x4 o[4];
    float lsum[4];
    int t = -1, t0 = 0;

    auto flush = [&](int tt) {
        float lr[4];
        #pragma unroll
        for (int r = 0; r < 4; ++r) {
            float s = lsum[r];
            s += __shfl_xor(s, 1); s += __shfl_xor(s, 2);
            s += __shfl_xor(s, 4); s += __shfl_xor(s, 8);
            lr[r] = s;
        }
        const bool whole = (d_S[tt] >> 2) == ((d_S[tt + 1] - 1) >> 2);
        if (whole) {           // all units of this tile in this block: finalize
            #pragma unroll
            for (int tn = 0; tn < 4; ++tn) {
                const int col = h * 64 + tn * 16 + l15;
                #pragma unroll
                for (int r = 0; r < 4; ++r) {
                    const int trow = tt * 64 + w * 16 + quad * 4 + r;
                    yb[(size_t)(b * 1024 + trow) * 1024 + col] = f2b(o[tn][r] / lr[r]);
                }
            }
        } else {               // partial: statically-indexed slot
            const int slot = blk - (d_S[tt] >> 2);
            const size_t sidx = (size_t)(bh * 19 + d_SB[tt] + slot);
            float* pob = po + (sidx << 12);
            #pragma unroll
            for (int tn = 0; tn < 4; ++tn)
                #pragma unroll
                for (int r = 0; r < 4; ++r)
                    pob[(w * 16 + quad * 4 + r) * 64 + tn * 16 + l15] = o[tn][r];
            if (l15 == 0) {
                float* lsb = lsp + (sidx << 6);
                #pragma unroll
                for (int r = 0; r < 4; ++r) lsb[w * 16 + quad * 4 + r] = lr[r];
            }
        }
    };

    #pragma unroll 1
    for (int ui = 0; ui < 4; ++ui) {
        const int u = blk * 4 + ui;
        int nt = (t < 0) ? 0 : t;
        while (d_S[nt + 1] <= u) ++nt;
        if (nt != t) {
            if (t >= 0) flush(t);
            t = nt; t0 = t * 64;
            const int trow = t0 + w * 16 + l15;
            const u16* qp = qkvb + (size_t)(b * 1024 + trow) * 3072 + h * 64 + quad * 8;
            qn[0] = *(const bf8*)qp;
            qn[1] = *(const bf8*)(qp + 32);
            #pragma unroll
            for (int tn = 0; tn < 4; ++tn)
                #pragma unroll
                for (int j = 0; j < 4; ++j) o[tn][j] = 0.f;
            #pragma unroll
            for (int r = 0; r < 4; ++r) lsum[r] = 0.f;
        }
        const int c = u - d_S[t];
        const int s0 = c << 7;
        const int diff = t0 - s0;                 // >= 0, multiple of 64

        __syncthreads();    // bar1: prior unit's LDS reads retired (drain ~free)

        // ---- issue K DMA only (16 KB contiguous) ----
        {
            const size_t kbase = ((size_t)(bh * 64 + (s0 >> 4)) << 1) * 512;
            #pragma unroll
            for (int i = 0; i < 4; ++i)
                async16(Kp + kbase + (i * 256 + tid) * 8, &KVs[(i * 256 + tid) * 8]);
        }

        // ---- S2 = Q @ EK^T (global EKP stream; covers K DMA latency) ----
        f32x4 s2[9] = {};
        {
            const int kb = (diff >> 4) + w;       // k16 base
            #pragma unroll
            for (int j = 0; j < 9; ++j) {
                #pragma unroll
                for (int kc = 0; kc < 2; ++kc)
                    s2[j] = __builtin_amdgcn_mfma_f32_16x16x32_bf16(
                        qn[kc], EKPF[(((kb + j) << 1) + kc) * 64 + L], s2[j], 0, 0, 0);
            }
        }
        #pragma unroll
        for (int j = 0; j < 9; ++j)
            #pragma unroll
            for (int r = 0; r < 4; ++r)
                S2l[(quad * 4 + r) * 148 + j * 16 + l15] = f2b(s2[j][r]);

        // ---- issue V DMA LAST (latency hides under S1 + softmax + scatter) ----
        __builtin_amdgcn_sched_barrier(0);   // pin V issue after all S2 loads
        {
            const int vb = bh * 128 + (s0 >> 5);
            #pragma unroll
            for (int i = 0; i < 4; ++i)
                async16(Vp + ((size_t)(vb + i * 32) * 512 + tid * 8),
                        &KVs[8192 + i * 2048 + tid * 8]);
        }

        // ---- wait K only (4 oldest VMEM; V stays in flight), rendezvous ----
        asm volatile("s_waitcnt vmcnt(4)" ::: "memory");
        __builtin_amdgcn_s_barrier();
        __builtin_amdgcn_sched_barrier(0);

        // ---- S1 = Q @ (K/8)^T from LDS ----
        f32x4 s1[8];
        __builtin_amdgcn_s_setprio(1);
        #pragma unroll
        for (int tn = 0; tn < 8; ++tn) {
            f32x4 z = {};
            #pragma unroll
            for (int kc = 0; kc < 2; ++kc) {
                const bf8 kf = *(const bf8*)&KVs[((tn << 1) + kc) * 512 + L * 8];
                z = __builtin_amdgcn_mfma_f32_16x16x32_bf16(qn[kc], kf, z, 0, 0, 0);
            }
            s1[tn] = z;
        }
        __builtin_amdgcn_s_setprio(0);

        // ---- logits + mask + p = exp(logit - 4); per-lane partial sums ----
        #pragma unroll
        for (int tn = 0; tn < 8; ++tn) {
            const int cl = tn * 16 + l15;
            #pragma unroll
            for (int r = 0; r < 4; ++r) {
                const int row = quad * 4 + r;
                float v = s1[tn][r] + b2f(S2l[row * 148 + (row - cl + 127)]);
                if (cl > diff + w * 16 + row) v = -1e30f;
                float p = __expf(v - 4.0f);       // masked -> 0
                s1[tn][r] = p;
                lsum[r] += p;
            }
        }

        // ---- scatter P in MFMA A-layout (clobbers dead S2l region) ----
        #pragma unroll
        for (int tn = 0; tn < 8; ++tn) {
            const int cl = tn * 16 + l15;
            #pragma unroll
            for (int r = 0; r < 4; ++r) {
                const int row = quad * 4 + r;
                Pl[((cl >> 5) << 9) + (((cl >> 3) & 3) << 7) + (row << 3) + (cl & 7)]
                    = f2b(s1[tn][r]);
            }
        }
        // ---- read P fragments (in-order DS: reads precede overlay writes) ----
        bf8 pa[4];
        #pragma unroll
        for (int kc = 0; kc < 4; ++kc) pa[kc] = ((const bf8*)Pl)[kc * 64 + L];

        // ---- rebuild overlay as sheared P' (zero pads, then scatter) ----
        #pragma unroll
        for (int i = 0; i < 5; ++i)
            ((uint4*)Ppl)[i * 64 + L] = make_uint4(0, 0, 0, 0);
        #pragma unroll
        for (int tn = 0; tn < 8; ++tn) {
            const int cl = tn * 16 + l15;
            #pragma unroll
            for (int r = 0; r < 4; ++r) {
                const int row = quad * 4 + r;
                const int dc = (w & 1) * 16 + row - cl + 127;   // [0,158]
                Ppl[((dc >> 5) << 9) + (((dc >> 3) & 3) << 7) + (row << 3) + (dc & 7)]
                    = f2b(s1[tn][r]);
            }
        }

        __syncthreads();    // bar3: V visible to all waves (drain ~free, V landed)
        __builtin_amdgcn_sched_barrier(0);

        // ---- O += P @ V (V frags from LDS) ----
        __builtin_amdgcn_s_setprio(1);
        {
            #pragma unroll
            for (int tn = 0; tn < 4; ++tn) {
                #pragma unroll
                for (int kc = 0; kc < 4; ++kc) {
                    const bf8 vf = *(const bf8*)&KVs[8192 + (tn * 4 + kc) * 512 + L * 8];
                    o[tn] = __builtin_amdgcn_mfma_f32_16x16x32_bf16(
                        pa[kc], vf, o[tn], 0, 0, 0);
                }
            }
        }
        // ---- O += P' @ EV (global EVP stream) ----
        {
            bf8 pb[5];
            #pragma unroll
            for (int kc = 0; kc < 5; ++kc) pb[kc] = ((const bf8*)Ppl)[kc * 64 + L];
            const int eb = (diff >> 5) + (w >> 1);
            #pragma unroll
            for (int tn = 0; tn < 4; ++tn) {
                #pragma unroll
                for (int kc = 0; kc < 5; ++kc)
                    o[tn] = __builtin_amdgcn_mfma_f32_16x16x32_bf16(
                        pb[kc], EVPF[(tn * 36 + eb + kc) * 64 + L], o[tn], 0, 0, 0);
            }
        }
        __builtin_amdgcn_s_setprio(0);
    }
    flush(t);
}

// ---------------- combine partial (o, lsum) slots for split tiles, normalize -------
__global__ __launch_bounds__(256) void attn_reduce(const float* __restrict__ po,
                                                   const float* __restrict__ lsp,
                                                   u16* __restrict__ yb) {
    const int gi = blockIdx.x;                    // 0 -> tile 4, i -> tile i+7
    const int t = (gi == 0) ? 4 : (gi + 7);
    const int bh = blockIdx.y, b = bh >> 4, h = bh & 15;
    const int ns = (t == 12) ? 3 : 2;
    const size_t base = (size_t)(bh * 19 + d_SB[t]);
    const float* pob = po + (base << 12);
    const float* lsb = lsp + (base << 6);
    #pragma unroll 1
    for (int i = 0; i < 16; ++i) {
        const int idx = i * 256 + threadIdx.x;
        const int row = idx >> 6, col = idx & 63;
        float acc = 0.f, lacc = 0.f;
        for (int s = 0; s < ns; ++s) {
            acc  += pob[(s << 12) + idx];
            lacc += lsb[(s << 6) + row];
        }
        yb[(size_t)(b * 1024 + t * 64 + row) * 1024 + h * 64 + col] = f2b(acc / lacc);
    }
}

extern "C" void kernel_launch(void* const* d_in, const int* in_sizes, int n_in,
                              void* d_out, int out_size, void* d_ws, size_t ws_size,
                              hipStream_t stream) {
    const float* x      = (const float*)d_in[0];
    const float* w_attn = (const float*)d_in[1];
    const float* w_proj = (const float*)d_in[2];
    const float* embk   = (const float*)d_in[3];
    const float* embv   = (const float*)d_in[4];
    float* out = (float*)d_out;

    u16* wsb   = (u16*)d_ws;
    u16* qkvb  = wsb;                  // 4096*3072            = 12582912
    u16* xb    = qkvb + 12582912;      // 4096*1024            = 4194304
    u16* ymidb = xb;                   // aliases xb (xb dead after gemm1)
    u16* waT   = xb + 4194304;         // 3072*1024            = 3145728
    u16* wpT   = waT + 3145728;        // 1024*1024            = 1048576
    u16* Vt    = wpT + 1048576;        // (slot unused now; layout kept stable)
    u16* Kp    = Vt + 4194304;         // 64*64*2*512          = 4194304
    u16* Vp    = Kp + 4194304;         // 64*4*32*512          = 4194304
    u16* EKP   = Vp + 4194304;         // 72*2*512             = 73728
    u16* EVP   = EKP + 73728;          // 4*36*512             = 73728
    float* po  = (float*)(EVP + 73728);// 64*19*4096 f32       = 4980736 f32
    float* lsp = po + 4980736;         // 64*19*64 f32         = 77824 f32

    prep_all<<<dim3(5192), 256, 0, stream>>>(x, embk, embv, w_attn, w_proj,
                                             xb, EKP, EVP, waT, wpT);
    gemm_mfma<u16><<<dim3(24, 32), 256, 0, stream>>>(xb, waT, qkvb, 4096, 3072, 1024);
    pack_kv2<<<dim3(4096), 256, 0, stream>>>(qkvb, Kp, Vp);
    attn_mfma<<<dim3(18, 64), 256, 0, stream>>>(qkvb, Kp, Vp, EKP, EVP, ymidb, po, lsp);
    attn_reduce<<<dim3(9, 64), 256, 0, stream>>>(po, lsp, ymidb);
    gemm_mfma64<float><<<dim3(8, 64), 256, 0, stream>>>(ymidb, wpT, out, 4096, 1024, 1024);
}